// Round 19
// baseline (132.263 us; speedup 1.0000x reference)
//
#include <hip/hip_runtime.h>
#include <hip/hip_fp16.h>
#include <cstdint>
#include <cmath>

#define BB 64
#define SS 256
#define NN 512
#define MAXC 64   // max nonzeros per adj column/row (mean ~25.6, true max ~46)
#define MAXC1 (MAXC + 1)

typedef float f32x4 __attribute__((ext_vector_type(4)));
typedef _Float16 half8 __attribute__((ext_vector_type(8)));

__device__ __forceinline__ unsigned short f2h(float f) {
  return __half_as_ushort(__float2half(f));
}
__device__ __forceinline__ float h2f(unsigned short u) {
  return __half2float(__ushort_as_half(u));
}
__device__ __forceinline__ float2 unpackh2(uint32_t u) {
  return make_float2(__half2float(__ushort_as_half((unsigned short)(u & 0xffffu))),
                     __half2float(__ushort_as_half((unsigned short)(u >> 16))));
}

__device__ __forceinline__ void gload_lds16(const void* g, void* s) {
  __builtin_amdgcn_global_load_lds(
      (const __attribute__((address_space(1))) uint32_t*)g,
      (__attribute__((address_space(3))) uint32_t*)s, 16, 0, 0);
}

// ---------------------------------------------------------------------------
// K0: per-column adjacency lists (ascending m, ballot compaction).
// Also emits colpos[m][n] = slot of m in column n, and colpos[n][n] = diag slot.
__global__ __launch_bounds__(256) void k_collist(const float* __restrict__ adj,
                                                 int* __restrict__ col_idx,
                                                 int* __restrict__ col_cnt,
                                                 int* __restrict__ colpos) {
  const int n = blockIdx.x * 4 + (threadIdx.x >> 6);
  const int lane = threadIdx.x & 63;
  int cnt = 0;
  for (int m0 = 0; m0 < NN; m0 += 64) {
    const int m = m0 + lane;
    const float a = adj[(size_t)m * NN + n];
    unsigned long long mask = __ballot(a != 0.0f);
    const int prefix = __popcll(mask & ((1ull << lane) - 1ull));
    if (a != 0.0f && cnt + prefix < MAXC) {
      col_idx[n * MAXC + cnt + prefix] = m;
      colpos[(size_t)m * NN + n] = cnt + prefix;
    }
    cnt += __popcll(mask);
  }
  if (cnt > MAXC) cnt = MAXC;
  if (lane == 0) {
    col_cnt[n] = cnt;
    colpos[(size_t)n * NN + n] = cnt;   // diag slot of column n
  }
}

// K0a: per-row lists with resolved attv slot addresses.
// rsrc[m][i] = n*65 + colpos[m][n]; rn[m][i] = n; last entry = diag (n=m).
__global__ __launch_bounds__(256) void k_rowprep(const float* __restrict__ adj,
                                                 const int* __restrict__ colpos,
                                                 int* __restrict__ rsrc_a,
                                                 int* __restrict__ rn_a,
                                                 int* __restrict__ nnz_row) {
  const int m = blockIdx.x * 4 + (threadIdx.x >> 6);
  const int wave = threadIdx.x >> 6;
  const int lane = threadIdx.x & 63;
  __shared__ int lsw[4][MAXC];
  int cnt = 0;
  for (int n0 = 0; n0 < NN; n0 += 64) {
    const float a = adj[(size_t)m * NN + n0 + lane];
    unsigned long long mask = __ballot(a != 0.0f);
    const int prefix = __popcll(mask & ((1ull << lane) - 1ull));
    if (a != 0.0f && cnt + prefix < MAXC - 1) lsw[wave][cnt + prefix] = n0 + lane;
    cnt += __popcll(mask);
  }
  if (cnt > MAXC - 1) cnt = MAXC - 1;   // leave room for diag
  if (lane < cnt) {
    const int n = lsw[wave][lane];
    const int pos = colpos[(size_t)m * NN + n];
    rsrc_a[m * MAXC + lane] = n * MAXC1 + pos;
    rn_a[m * MAXC + lane] = n;
  }
  if (lane == cnt) {
    const int pos = colpos[(size_t)m * NN + m];
    rsrc_a[m * MAXC + cnt] = m * MAXC1 + pos;
    rn_a[m * MAXC + cnt] = m;
    nnz_row[m] = cnt + 1;
  }
}

// K0b: packed W sub-blocks + per-block prefix scan. 4 waves split the ji-loop.
__global__ __launch_bounds__(256) void k_wsub(const float* __restrict__ W,
                                              const int* __restrict__ col_idx,
                                              const int* __restrict__ col_cnt,
                                              int* __restrict__ col_off,
                                              float* __restrict__ Wsub) {
  const int n = blockIdx.x;
  const int t = threadIdx.x;
  const int wave = t >> 6, lane = t & 63;
  __shared__ int lsh[MAXC];
  __shared__ int preSh;
  const int c = col_cnt[n];
  if (wave == 0) {
    int pre = 0;
#pragma unroll
    for (int i0 = 0; i0 < NN; i0 += 64) {
      const int i = i0 + lane;
      const int cc = col_cnt[i];
      pre += (i < n) ? cc * cc : 0;
    }
#pragma unroll
    for (int off = 32; off; off >>= 1) pre += __shfl_xor(pre, off);
    if (lane == 0) { col_off[n] = pre; preSh = pre; }
    if (lane < c) lsh[lane] = col_idx[n * MAXC + lane];
  }
  __syncthreads();
  if (lane < c) {
    const float* Wm = W + (size_t)lsh[lane] * NN;
    float* dst = Wsub + preSh + lane;
    for (int ji = wave; ji < c; ji += 4)
      dst[(size_t)ji * c] = Wm[lsh[ji]];
  }
}

// ---------------------------------------------------------------------------
// K1: fused x-prep: x (B,S,N) f32 -> xp (B*S,512) f16, xt (B,N,S) f16.
__global__ __launch_bounds__(256) void k_xprep(const float* __restrict__ x,
                                               unsigned short* __restrict__ xp,
                                               unsigned short* __restrict__ xt) {
  __shared__ float tile[32][33];
  const int b = blockIdx.z;
  const int s0 = blockIdx.x * 32, n0 = blockIdx.y * 32;
  const float* xb = x + (size_t)b * SS * NN;
  const int tx = threadIdx.x, ty = threadIdx.y;  // (32,8)
#pragma unroll
  for (int i = ty; i < 32; i += 8) {
    const float v = xb[(size_t)(s0 + i) * NN + n0 + tx];
    tile[i][tx] = v;
    xp[(size_t)(b * SS + s0 + i) * 512 + n0 + tx] = f2h(v);
  }
  __syncthreads();
  unsigned short* xtb = xt + (size_t)b * NN * SS;
#pragma unroll
  for (int i = ty; i < 32; i += 8)
    xtb[(size_t)(n0 + i) * SS + s0 + tx] = f2h(tile[tx][i]);
}

// K1b: weight conversion to f16 (both Wq and Wk)
__global__ __launch_bounds__(128) void k_wsplit(const float* __restrict__ Wq,
                                                const float* __restrict__ Wk,
                                                unsigned short* __restrict__ Wqp,
                                                unsigned short* __restrict__ Wkp) {
  const int n = blockIdx.x;
  const float* src = blockIdx.y ? Wk : Wq;
  unsigned short* dst = blockIdx.y ? Wkp : Wqp;
  const int k = threadIdx.x * 4;
  float4 v = *(const float4*)(src + (size_t)n * NN + k);
  ushort4 o;
  o.x = f2h(v.x); o.y = f2h(v.y); o.z = f2h(v.z); o.w = f2h(v.w);
  *(ushort4*)(dst + (size_t)n * 512 + k) = o;
}

// ---------------------------------------------------------------------------
// K3: BOTH Linears in one block (shared X staging), 2-phase prefetch pipeline.
// Single-pass f16 GEMM (K=512 -> 16 K-steps). Q out f16, K out f16.
__global__ __launch_bounds__(256, 2) void k_lin2(const unsigned short* __restrict__ Wqp,
                                                 const unsigned short* __restrict__ Wkp,
                                                 const float* __restrict__ bq,
                                                 const float* __restrict__ bk,
                                                 const unsigned short* __restrict__ xp,
                                                 unsigned short* __restrict__ Qt,
                                                 unsigned short* __restrict__ Kt) {
  __shared__ __align__(16) char sm[49152];
  const int t = threadIdx.x;
  const int w = t >> 6, l = t & 63;
  const int id = blockIdx.x;
  const int xcd = id & 7, sub = id >> 3;
  const int bn0 = (xcd * 16 + (sub >> 2)) * 128;  // r = b*256+s
  const int bm0 = (sub & 3) * 128;                // n

  const int swz = (((l & 3) ^ ((l >> 3) & 3))) * 16;
  const char* srcb[6];
  char* dstb[6];
#pragma unroll
  for (int i = 0; i < 6; i++) {
    const int ch = w * 6 + i;
    const int panel = ch >> 3, rowgrp = ch & 7;
    const int row = rowgrp * 16 + (l >> 2);
    const char* g0 = (panel == 0) ? (const char*)Wqp
                   : (panel == 1) ? (const char*)Wkp : (const char*)xp;
    const int gr = ((panel == 2) ? bn0 : bm0) + row;
    srcb[i] = g0 + (size_t)gr * 1024 + swz;
    dstb[i] = sm + panel * 8192 + rowgrp * 1024 + l * 16;
  }

  const int fr = l & 15, fg = l >> 4;
  const int mrow = (w >> 1) * 64, ncol = (w & 1) * 64;
  const int slot = (fg ^ ((fr >> 1) & 3)) * 16;
  int offQ[4], offK[4], offB[4];
#pragma unroll
  for (int fm = 0; fm < 4; fm++) {
    offQ[fm] = (mrow + fm * 16 + fr) * 64 + slot;
    offK[fm] = 8192 + (mrow + fm * 16 + fr) * 64 + slot;
    offB[fm] = 16384 + (ncol + fm * 16 + fr) * 64 + slot;
  }

  f32x4 accq[4][4], acck[4][4];
#pragma unroll
  for (int i = 0; i < 4; i++)
#pragma unroll
    for (int j = 0; j < 4; j++) { accq[i][j] = (f32x4)0.0f; acck[i][j] = (f32x4)0.0f; }

#pragma unroll
  for (int i = 0; i < 6; i++) gload_lds16(srcb[i], dstb[i]);
  __syncthreads();

  int cur = 0;
  for (int kk = 0; kk < 16; kk++) {
    if (kk + 1 < 16) {
      const int ko = (kk + 1) * 64;
      const int boff = (cur ^ 1) * 24576;
#pragma unroll
      for (int i = 0; i < 6; i++)
        gload_lds16(srcb[i] + ko, dstb[i] + boff);
    }
    const char* base = sm + cur * 24576;
    half8 afq[4], afk[4];
#pragma unroll
    for (int fm = 0; fm < 4; fm++) {
      afq[fm] = *(const half8*)(base + offQ[fm]);
      afk[fm] = *(const half8*)(base + offK[fm]);
    }
#pragma unroll
    for (int fn = 0; fn < 4; fn++) {
      const half8 bv = *(const half8*)(base + offB[fn]);
#pragma unroll
      for (int fm = 0; fm < 4; fm++) {
        accq[fm][fn] = __builtin_amdgcn_mfma_f32_16x16x32_f16(afq[fm], bv, accq[fm][fn], 0, 0, 0);
        acck[fm][fn] = __builtin_amdgcn_mfma_f32_16x16x32_f16(afk[fm], bv, acck[fm][fn], 0, 0, 0);
      }
    }
    __syncthreads();
    cur ^= 1;
  }

  // epilogue: D col = lane&15 (-> r), row = (lane>>4)*4+q (-> n)
  const int b = bn0 >> 8;
  const int sbase = (bn0 & 255) + ncol;
#pragma unroll
  for (int fm = 0; fm < 4; fm++) {
#pragma unroll
    for (int q = 0; q < 4; q++) {
      const int n = bm0 + mrow + fm * 16 + fg * 4 + q;
      const float bvq = bq[n];
      const float bvk = bk[n];
#pragma unroll
      for (int fn = 0; fn < 4; fn++) {
        const int s = sbase + fn * 16 + fr;
        Qt[((size_t)b * NN + n) * SS + s] = f2h(accq[fm][fn][q] + bvq);
        Kt[((size_t)b * NN + n) * SS + s] = f2h(acck[fm][fn][q] + bvk);
      }
    }
  }
}

// ---------------------------------------------------------------------------
// K3b: dense Gram per batch: ST[b][n][j] = <Q[b,n,:], K[b,j,:]>, f16 out.
__global__ __launch_bounds__(256, 2) void k_gram(const unsigned short* __restrict__ Qt,
                                                 const unsigned short* __restrict__ Kt,
                                                 unsigned short* __restrict__ ST) {
  __shared__ __align__(16) char sm[32768];
  const int t = threadIdx.x;
  const int w = t >> 6, l = t & 63;
  const int id = blockIdx.x;
  const int xcd = id & 7, rest = id >> 3;       // rest 0..127
  const int batch = (xcd << 3) + (rest >> 4);
  const int tile = rest & 15;
  const int m0 = (tile >> 2) * 128;             // n rows (A = Q)
  const int n0 = (tile & 3) * 128;              // j rows (B = K)

  const int swz = (((l & 3) ^ ((l >> 3) & 3))) * 16;
  const char* srcb[4];
  char* dstb[4];
#pragma unroll
  for (int i = 0; i < 4; i++) {
    const int ch = w * 4 + i;                   // 16 chunks: A(0..7), B(8..15)
    const int panel = ch >> 3, rowgrp = ch & 7;
    const int row = rowgrp * 16 + (l >> 2);
    const char* g0 = panel ? (const char*)Kt : (const char*)Qt;
    const int gr = (panel ? n0 : m0) + row;
    srcb[i] = g0 + ((size_t)batch * 512 + gr) * 512 + swz;
    dstb[i] = sm + panel * 8192 + rowgrp * 1024 + l * 16;
  }

  const int fr = l & 15, fg = l >> 4;
  const int mrow = (w >> 1) * 64, ncol = (w & 1) * 64;
  const int slot = (fg ^ ((fr >> 1) & 3)) * 16;
  int offA[4], offB[4];
#pragma unroll
  for (int fm = 0; fm < 4; fm++) {
    offA[fm] = (mrow + fm * 16 + fr) * 64 + slot;
    offB[fm] = 8192 + (ncol + fm * 16 + fr) * 64 + slot;
  }

  f32x4 acc[4][4];
#pragma unroll
  for (int i = 0; i < 4; i++)
#pragma unroll
    for (int j = 0; j < 4; j++) acc[i][j] = (f32x4)0.0f;

#pragma unroll
  for (int i = 0; i < 4; i++) gload_lds16(srcb[i], dstb[i]);
  __syncthreads();

  int cur = 0;
  for (int kk = 0; kk < 8; kk++) {
    if (kk + 1 < 8) {
      const int ko = (kk + 1) * 64;
      const int boff = (cur ^ 1) * 16384;
#pragma unroll
      for (int i = 0; i < 4; i++)
        gload_lds16(srcb[i] + ko, dstb[i] + boff);
    }
    const char* base = sm + cur * 16384;
    half8 af[4];
#pragma unroll
    for (int fm = 0; fm < 4; fm++)
      af[fm] = *(const half8*)(base + offA[fm]);
#pragma unroll
    for (int fn = 0; fn < 4; fn++) {
      const half8 bv = *(const half8*)(base + offB[fn]);
#pragma unroll
      for (int fm = 0; fm < 4; fm++)
        acc[fm][fn] = __builtin_amdgcn_mfma_f32_16x16x32_f16(af[fm], bv, acc[fm][fn], 0, 0, 0);
    }
    __syncthreads();
    cur ^= 1;
  }

  unsigned short* STb = ST + (size_t)batch * NN * NN;
#pragma unroll
  for (int fm = 0; fm < 4; fm++) {
#pragma unroll
    for (int q = 0; q < 4; q++) {
      const int n = m0 + mrow + fm * 16 + fg * 4 + q;
#pragma unroll
      for (int fn = 0; fn < 4; fn++) {
        const int j = n0 + ncol + fn * 16 + fr;
        STb[(size_t)n * NN + j] = f2h(acc[fm][fn][q]);
      }
    }
  }
}

// ---------------------------------------------------------------------------
// K4: fused sparse stage — ONE WAVE per (n,b) column; 4 batches per block.
// Writes the softmax column COMPACTLY to attv (coalesced), no Att scatter.
__global__ __launch_bounds__(256) void k_fused(const unsigned short* __restrict__ ST,
                                               const unsigned short* __restrict__ xt,
                                               const float* __restrict__ Wsub,
                                               const float* __restrict__ pnw,
                                               const int* __restrict__ col_idx,
                                               const int* __restrict__ col_cnt,
                                               const int* __restrict__ col_off,
                                               float* __restrict__ attv,
                                               float* __restrict__ agg) {
  const int id = blockIdx.x;          // 0..8191
  const int xcd = id & 7;
  const int r = id >> 3;
  const int n = r & 511;
  const int bgrp = r >> 9;
  const int t = threadIdx.x;
  const int wave = t >> 6, lane = t & 63;
  const int b = (xcd << 3) + (bgrp << 2) + wave;

  __shared__ int   lsh[MAXC + 1];
  __shared__ int   lshB[MAXC + 1];
  __shared__ float Wsh[MAXC * MAXC];
  __shared__ float vsh[4][MAXC];
  __shared__ float ash[4][MAXC + 1];

  const int c = col_cnt[n];
  if (t < c) {
    const int v = col_idx[n * MAXC + t];
    lsh[t] = v;
    lshB[t] = v << 9;
  }
  if (t == c) { lsh[c] = n; lshB[c] = n << 9; }
  {
    const int cc = c * c;
    const float* Wp = Wsub + col_off[n];
    for (int i = t; i < cc; i += 256) Wsh[i] = Wp[i];
  }
  __syncthreads();   // the only block barrier

  // Step 1: v[ji] = ST[b][n][lsh[ji]] — one 2B load per lane from one row.
  const unsigned short* STrow = ST + ((size_t)b * NN + n) * NN;
  if (lane < c) vsh[wave][lane] = h2f(STrow[lsh[lane]]);

  // Step 2: aval[mi] = sum_ji Wsh[ji*c+mi] * v[ji]  (lane = mi)
  float aval = 0.0f;
  if (lane < c) {
    for (int ji = 0; ji < c; ji++)
      aval += Wsh[ji * c + lane] * vsh[wave][ji];
  }

  // Step 3: in-wave softmax over {aval[0..c), pnw[n] at diag, 512-c-1 zeros}
  const float dlg = pnw[n];
  float mval = (lane < c) ? aval : -INFINITY;
#pragma unroll
  for (int off = 32; off; off >>= 1) mval = fmaxf(mval, __shfl_xor(mval, off));
  const float colmax = fmaxf(mval, fmaxf(dlg, 0.0f));
  const float e = (lane < c) ? __expf(aval - colmax) : 0.0f;
  float sum = e;
#pragma unroll
  for (int off = 32; off; off >>= 1) sum += __shfl_xor(sum, off);
  const float denom = sum + __expf(dlg - colmax)
                    + (float)(NN - c - 1) * __expf(-colmax);
  const float inv = 1.0f / denom;

  // Step 4/5: compact column write (coalesced 4B/lane)
  float* av = attv + ((size_t)b * NN + n) * MAXC1;
  if (lane < c) {
    const float attval = e * inv;
    ash[wave][lane] = attval;
    av[lane] = attval;
  }
  if (lane == c) {
    const float dv = __expf(dlg - colmax) * inv;
    ash[wave][c] = dv;
    av[c] = dv;
  }

  // Step 6: agg[b,n,:] = sum_{mi<=c} ash[mi] * xt[b,lsh[mi],:]
  const char* xtb = (const char*)(xt + (size_t)b * NN * SS);
  f32x4 acc = (f32x4)0.0f;
  for (int mi = 0; mi <= c; mi++) {
    const float a = ash[wave][mi];
    const uint2 v = *(const uint2*)(xtb + lshB[mi] + lane * 8);
    const float2 x01 = unpackh2(v.x);
    const float2 x23 = unpackh2(v.y);
    acc.x += a * x01.x;
    acc.y += a * x01.y;
    acc.z += a * x23.x;
    acc.w += a * x23.y;
  }
  *(f32x4*)(agg + ((size_t)b * NN + n) * SS + lane * 4) = acc;
}

// ---------------------------------------------------------------------------
// K5: Att row materialization — one wave per (b, m): build 512-float row in
// LDS (zeros + gathered attv values), write 2KB coalesced.
// NOTE: the zero-init (f32x4 stores), sparse fill (float stores), and readback
// (f32x4 loads) are MIXED-TYPE accesses to the same LDS array — barriers
// between phases are REQUIRED (TBAA may otherwise reorder/forward past the
// float scatter; this was R18's Att corruption).
__global__ __launch_bounds__(256) void k_attw(const float* __restrict__ attv,
                                              const int* __restrict__ rsrc_a,
                                              const int* __restrict__ rn_a,
                                              const int* __restrict__ nnz_row,
                                              float* __restrict__ Att) {
  const int id = blockIdx.x;            // 0..8191
  const int xcd = id & 7;
  const int rest = id >> 3;             // 0..1023
  const int b = (xcd << 3) + (rest >> 7);
  const int wave = threadIdx.x >> 6;
  const int lane = threadIdx.x & 63;
  const int m = (rest & 127) * 4 + wave;
  __shared__ float row[4][512];
  const f32x4 z = (f32x4)0.0f;
  *(f32x4*)&row[wave][lane * 8] = z;
  *(f32x4*)&row[wave][lane * 8 + 4] = z;
  __syncthreads();   // order zero-init (f32x4) vs scatter (float)
  const int nnz = nnz_row[m];
  if (lane < nnz) {
    const int rs = rsrc_a[m * MAXC + lane];
    const int rn = rn_a[m * MAXC + lane];
    row[wave][rn] = attv[(size_t)b * (NN * MAXC1) + rs];
  }
  __syncthreads();   // order scatter (float) vs readback (f32x4)
  float* dst = Att + ((size_t)b * NN + m) * NN;
  *(f32x4*)(dst + lane * 8)     = *(const f32x4*)&row[wave][lane * 8];
  *(f32x4*)(dst + lane * 8 + 4) = *(const f32x4*)&row[wave][lane * 8 + 4];
}

// ---------------------------------------------------------------------------
extern "C" void kernel_launch(void* const* d_in, const int* in_sizes, int n_in,
                              void* d_out, int out_size, void* d_ws, size_t ws_size,
                              hipStream_t stream) {
  const float* x    = (const float*)d_in[0];
  const float* adj  = (const float*)d_in[1];
  const float* W    = (const float*)d_in[2];
  const float* pnw  = (const float*)d_in[3];
  const float* Wq_w = (const float*)d_in[4];
  const float* Wq_b = (const float*)d_in[5];
  const float* Wk_w = (const float*)d_in[6];
  const float* Wk_b = (const float*)d_in[7];

  float* agg = (float*)d_out;                        // (B,N,S)
  float* Att = (float*)d_out + (size_t)BB * NN * SS; // (B,N,N)

  char* p = (char*)d_ws;
  unsigned short* xp  = (unsigned short*)p; p += (size_t)BB * SS * 512 * 2;   // 16.78 MB
  unsigned short* Wqp = (unsigned short*)p; p += (size_t)NN * 512 * 2;        // 0.52 MB
  unsigned short* Wkp = (unsigned short*)p; p += (size_t)NN * 512 * 2;        // 0.52 MB
  unsigned short* Qt  = (unsigned short*)p; p += (size_t)BB * NN * SS * 2;    // 16.78 MB
  unsigned short* Kt  = (unsigned short*)p; p += (size_t)BB * NN * SS * 2;    // 16.78 MB
  unsigned short* xt  = (unsigned short*)p; p += (size_t)BB * NN * SS * 2;    // 16.78 MB
  unsigned short* ST  = (unsigned short*)p; p += (size_t)BB * NN * NN * 2;    // 33.55 MB
  float* Wsub = (float*)p; p += (size_t)NN * MAXC * MAXC * 4;                 // 8.39 MB
  float* attv = (float*)p; p += (size_t)BB * NN * MAXC1 * 4;                  // 8.52 MB
  int* colpos = (int*)p; p += (size_t)NN * NN * 4;                            // 1.05 MB
  int* col_idx = (int*)p; p += (size_t)NN * MAXC * 4;
  int* rsrc_a = (int*)p; p += (size_t)NN * MAXC * 4;
  int* rn_a   = (int*)p; p += (size_t)NN * MAXC * 4;
  int* col_cnt = (int*)p; p += NN * 4;
  int* nnz_row = (int*)p; p += NN * 4;
  int* col_off = (int*)p;

  k_collist<<<dim3(NN / 4), dim3(256), 0, stream>>>(adj, col_idx, col_cnt, colpos);
  k_rowprep<<<dim3(NN / 4), dim3(256), 0, stream>>>(adj, colpos, rsrc_a, rn_a, nnz_row);
  k_wsub<<<dim3(NN), dim3(256), 0, stream>>>(W, col_idx, col_cnt, col_off, Wsub);
  k_xprep<<<dim3(SS / 32, NN / 32, BB), dim3(32, 8), 0, stream>>>(x, xp, xt);
  k_wsplit<<<dim3(NN, 2), dim3(128), 0, stream>>>(Wq_w, Wk_w, Wqp, Wkp);

  k_lin2<<<dim3(512), dim3(256), 0, stream>>>(Wqp, Wkp, Wq_b, Wk_b, xp, Qt, Kt);
  k_gram<<<dim3(1024), dim3(256), 0, stream>>>(Qt, Kt, ST);
  k_fused<<<dim3(8192), dim3(256), 0, stream>>>(ST, xt, Wsub, pnw,
                                                col_idx, col_cnt, col_off,
                                                attv, agg);
  k_attw<<<dim3(8192), dim3(256), 0, stream>>>(attv, rsrc_a, rn_a, nnz_row, Att);
}

// Round 20
// 117.320 us; speedup vs baseline: 1.1274x; 1.1274x over previous
//
#include <hip/hip_runtime.h>
#include <hip/hip_fp16.h>
#include <cstdint>
#include <cmath>

#define BB 64
#define SS 256
#define NN 512
#define MAXC 64   // max nonzeros per adj column (mean ~25.6, true max ~46)
#define MAXC1 (MAXC + 1)

typedef float f32x4 __attribute__((ext_vector_type(4)));
typedef _Float16 half8 __attribute__((ext_vector_type(8)));

__device__ __forceinline__ unsigned short f2h(float f) {
  return __half_as_ushort(__float2half(f));
}
__device__ __forceinline__ float h2f(unsigned short u) {
  return __half2float(__ushort_as_half(u));
}
__device__ __forceinline__ float2 unpackh2(uint32_t u) {
  return make_float2(__half2float(__ushort_as_half((unsigned short)(u & 0xffffu))),
                     __half2float(__ushort_as_half((unsigned short)(u >> 16))));
}

__device__ __forceinline__ void gload_lds16(const void* g, void* s) {
  __builtin_amdgcn_global_load_lds(
      (const __attribute__((address_space(1))) uint32_t*)g,
      (__attribute__((address_space(3))) uint32_t*)s, 16, 0, 0);
}

// ---------------------------------------------------------------------------
// K0: per-column adjacency lists (ascending m, ballot compaction).
// 4 columns per block (one per wave) for occupancy.
__global__ __launch_bounds__(256) void k_collist(const float* __restrict__ adj,
                                                 int* __restrict__ col_idx,
                                                 int* __restrict__ col_cnt) {
  const int n = blockIdx.x * 4 + (threadIdx.x >> 6);
  const int lane = threadIdx.x & 63;
  int cnt = 0;
  for (int m0 = 0; m0 < NN; m0 += 64) {
    const int m = m0 + lane;
    const float a = adj[(size_t)m * NN + n];
    unsigned long long mask = __ballot(a != 0.0f);
    const int prefix = __popcll(mask & ((1ull << lane) - 1ull));
    if (a != 0.0f && cnt + prefix < MAXC) col_idx[n * MAXC + cnt + prefix] = m;
    cnt += __popcll(mask);
  }
  if (lane == 0) col_cnt[n] = (cnt > MAXC) ? MAXC : cnt;
}

// K0b: packed W sub-blocks + per-block prefix scan. 4 waves split the ji-loop.
__global__ __launch_bounds__(256) void k_wsub(const float* __restrict__ W,
                                              const int* __restrict__ col_idx,
                                              const int* __restrict__ col_cnt,
                                              int* __restrict__ col_off,
                                              float* __restrict__ Wsub) {
  const int n = blockIdx.x;
  const int t = threadIdx.x;
  const int wave = t >> 6, lane = t & 63;
  __shared__ int lsh[MAXC];
  __shared__ int preSh;
  const int c = col_cnt[n];
  if (wave == 0) {
    int pre = 0;
#pragma unroll
    for (int i0 = 0; i0 < NN; i0 += 64) {
      const int i = i0 + lane;
      const int cc = col_cnt[i];
      pre += (i < n) ? cc * cc : 0;
    }
#pragma unroll
    for (int off = 32; off; off >>= 1) pre += __shfl_xor(pre, off);
    if (lane == 0) { col_off[n] = pre; preSh = pre; }
    if (lane < c) lsh[lane] = col_idx[n * MAXC + lane];
  }
  __syncthreads();
  if (lane < c) {
    const float* Wm = W + (size_t)lsh[lane] * NN;
    float* dst = Wsub + preSh + lane;
    for (int ji = wave; ji < c; ji += 4)
      dst[(size_t)ji * c] = Wm[lsh[ji]];
  }
}

// ---------------------------------------------------------------------------
// K1: fused x-prep: x (B,S,N) f32 -> xp (B*S,512) f16, xt (B,N,S) f16,
//     plus zero-fill of the Att output region.
__global__ __launch_bounds__(256) void k_xprep(const float* __restrict__ x,
                                               unsigned short* __restrict__ xp,
                                               unsigned short* __restrict__ xt,
                                               float* __restrict__ Att) {
  __shared__ float tile[32][33];
  const int b = blockIdx.z;
  const int s0 = blockIdx.x * 32, n0 = blockIdx.y * 32;
  const float* xb = x + (size_t)b * SS * NN;
  const int tx = threadIdx.x, ty = threadIdx.y;  // (32,8)
#pragma unroll
  for (int i = ty; i < 32; i += 8) {
    const float v = xb[(size_t)(s0 + i) * NN + n0 + tx];
    tile[i][tx] = v;
    xp[(size_t)(b * SS + s0 + i) * 512 + n0 + tx] = f2h(v);
  }
  {
    const int bid = (blockIdx.z * 16 + blockIdx.y) * 8 + blockIdx.x;
    const int t = ty * 32 + tx;
    f32x4* dst = (f32x4*)(Att + (size_t)bid * 2048);
    const f32x4 z = (f32x4)0.0f;
    dst[t] = z;
    dst[t + 256] = z;
  }
  __syncthreads();
  unsigned short* xtb = xt + (size_t)b * NN * SS;
#pragma unroll
  for (int i = ty; i < 32; i += 8)
    xtb[(size_t)(n0 + i) * SS + s0 + tx] = f2h(tile[tx][i]);
}

// K1b: weight conversion to f16 (both Wq and Wk)
__global__ __launch_bounds__(128) void k_wsplit(const float* __restrict__ Wq,
                                                const float* __restrict__ Wk,
                                                unsigned short* __restrict__ Wqp,
                                                unsigned short* __restrict__ Wkp) {
  const int n = blockIdx.x;
  const float* src = blockIdx.y ? Wk : Wq;
  unsigned short* dst = blockIdx.y ? Wkp : Wqp;
  const int k = threadIdx.x * 4;
  float4 v = *(const float4*)(src + (size_t)n * NN + k);
  ushort4 o;
  o.x = f2h(v.x); o.y = f2h(v.y); o.z = f2h(v.z); o.w = f2h(v.w);
  *(ushort4*)(dst + (size_t)n * 512 + k) = o;
}

// ---------------------------------------------------------------------------
// K3: BOTH Linears in one block (shared X staging), 2-phase prefetch pipeline.
// Single-pass f16 GEMM (K=512 -> 16 K-steps). Q out f16, K out f16.
__global__ __launch_bounds__(256, 2) void k_lin2(const unsigned short* __restrict__ Wqp,
                                                 const unsigned short* __restrict__ Wkp,
                                                 const float* __restrict__ bq,
                                                 const float* __restrict__ bk,
                                                 const unsigned short* __restrict__ xp,
                                                 unsigned short* __restrict__ Qt,
                                                 unsigned short* __restrict__ Kt) {
  __shared__ __align__(16) char sm[49152];
  const int t = threadIdx.x;
  const int w = t >> 6, l = t & 63;
  const int id = blockIdx.x;
  const int xcd = id & 7, sub = id >> 3;
  const int bn0 = (xcd * 16 + (sub >> 2)) * 128;  // r = b*256+s
  const int bm0 = (sub & 3) * 128;                // n

  const int swz = (((l & 3) ^ ((l >> 3) & 3))) * 16;
  const char* srcb[6];
  char* dstb[6];
#pragma unroll
  for (int i = 0; i < 6; i++) {
    const int ch = w * 6 + i;
    const int panel = ch >> 3, rowgrp = ch & 7;
    const int row = rowgrp * 16 + (l >> 2);
    const char* g0 = (panel == 0) ? (const char*)Wqp
                   : (panel == 1) ? (const char*)Wkp : (const char*)xp;
    const int gr = ((panel == 2) ? bn0 : bm0) + row;
    srcb[i] = g0 + (size_t)gr * 1024 + swz;
    dstb[i] = sm + panel * 8192 + rowgrp * 1024 + l * 16;
  }

  const int fr = l & 15, fg = l >> 4;
  const int mrow = (w >> 1) * 64, ncol = (w & 1) * 64;
  const int slot = (fg ^ ((fr >> 1) & 3)) * 16;
  int offQ[4], offK[4], offB[4];
#pragma unroll
  for (int fm = 0; fm < 4; fm++) {
    offQ[fm] = (mrow + fm * 16 + fr) * 64 + slot;
    offK[fm] = 8192 + (mrow + fm * 16 + fr) * 64 + slot;
    offB[fm] = 16384 + (ncol + fm * 16 + fr) * 64 + slot;
  }

  f32x4 accq[4][4], acck[4][4];
#pragma unroll
  for (int i = 0; i < 4; i++)
#pragma unroll
    for (int j = 0; j < 4; j++) { accq[i][j] = (f32x4)0.0f; acck[i][j] = (f32x4)0.0f; }

#pragma unroll
  for (int i = 0; i < 6; i++) gload_lds16(srcb[i], dstb[i]);
  __syncthreads();

  int cur = 0;
  for (int kk = 0; kk < 16; kk++) {
    if (kk + 1 < 16) {
      const int ko = (kk + 1) * 64;
      const int boff = (cur ^ 1) * 24576;
#pragma unroll
      for (int i = 0; i < 6; i++)
        gload_lds16(srcb[i] + ko, dstb[i] + boff);
    }
    const char* base = sm + cur * 24576;
    half8 afq[4], afk[4];
#pragma unroll
    for (int fm = 0; fm < 4; fm++) {
      afq[fm] = *(const half8*)(base + offQ[fm]);
      afk[fm] = *(const half8*)(base + offK[fm]);
    }
#pragma unroll
    for (int fn = 0; fn < 4; fn++) {
      const half8 bv = *(const half8*)(base + offB[fn]);
#pragma unroll
      for (int fm = 0; fm < 4; fm++) {
        accq[fm][fn] = __builtin_amdgcn_mfma_f32_16x16x32_f16(afq[fm], bv, accq[fm][fn], 0, 0, 0);
        acck[fm][fn] = __builtin_amdgcn_mfma_f32_16x16x32_f16(afk[fm], bv, acck[fm][fn], 0, 0, 0);
      }
    }
    __syncthreads();
    cur ^= 1;
  }

  // epilogue: D col = lane&15 (-> r), row = (lane>>4)*4+q (-> n)
  const int b = bn0 >> 8;
  const int sbase = (bn0 & 255) + ncol;
#pragma unroll
  for (int fm = 0; fm < 4; fm++) {
#pragma unroll
    for (int q = 0; q < 4; q++) {
      const int n = bm0 + mrow + fm * 16 + fg * 4 + q;
      const float bvq = bq[n];
      const float bvk = bk[n];
#pragma unroll
      for (int fn = 0; fn < 4; fn++) {
        const int s = sbase + fn * 16 + fr;
        Qt[((size_t)b * NN + n) * SS + s] = f2h(accq[fm][fn][q] + bvq);
        Kt[((size_t)b * NN + n) * SS + s] = f2h(acck[fm][fn][q] + bvk);
      }
    }
  }
}

// ---------------------------------------------------------------------------
// K3b: dense Gram per batch: ST[b][n][j] = <Q[b,n,:], K[b,j,:]>, f16 out.
__global__ __launch_bounds__(256, 2) void k_gram(const unsigned short* __restrict__ Qt,
                                                 const unsigned short* __restrict__ Kt,
                                                 unsigned short* __restrict__ ST) {
  __shared__ __align__(16) char sm[32768];
  const int t = threadIdx.x;
  const int w = t >> 6, l = t & 63;
  const int id = blockIdx.x;
  const int xcd = id & 7, rest = id >> 3;       // rest 0..127
  const int batch = (xcd << 3) + (rest >> 4);
  const int tile = rest & 15;
  const int m0 = (tile >> 2) * 128;             // n rows (A = Q)
  const int n0 = (tile & 3) * 128;              // j rows (B = K)

  const int swz = (((l & 3) ^ ((l >> 3) & 3))) * 16;
  const char* srcb[4];
  char* dstb[4];
#pragma unroll
  for (int i = 0; i < 4; i++) {
    const int ch = w * 4 + i;                   // 16 chunks: A(0..7), B(8..15)
    const int panel = ch >> 3, rowgrp = ch & 7;
    const int row = rowgrp * 16 + (l >> 2);
    const char* g0 = panel ? (const char*)Kt : (const char*)Qt;
    const int gr = (panel ? n0 : m0) + row;
    srcb[i] = g0 + ((size_t)batch * 512 + gr) * 512 + swz;
    dstb[i] = sm + panel * 8192 + rowgrp * 1024 + l * 16;
  }

  const int fr = l & 15, fg = l >> 4;
  const int mrow = (w >> 1) * 64, ncol = (w & 1) * 64;
  const int slot = (fg ^ ((fr >> 1) & 3)) * 16;
  int offA[4], offB[4];
#pragma unroll
  for (int fm = 0; fm < 4; fm++) {
    offA[fm] = (mrow + fm * 16 + fr) * 64 + slot;
    offB[fm] = 8192 + (ncol + fm * 16 + fr) * 64 + slot;
  }

  f32x4 acc[4][4];
#pragma unroll
  for (int i = 0; i < 4; i++)
#pragma unroll
    for (int j = 0; j < 4; j++) acc[i][j] = (f32x4)0.0f;

#pragma unroll
  for (int i = 0; i < 4; i++) gload_lds16(srcb[i], dstb[i]);
  __syncthreads();

  int cur = 0;
  for (int kk = 0; kk < 8; kk++) {
    if (kk + 1 < 8) {
      const int ko = (kk + 1) * 64;
      const int boff = (cur ^ 1) * 16384;
#pragma unroll
      for (int i = 0; i < 4; i++)
        gload_lds16(srcb[i] + ko, dstb[i] + boff);
    }
    const char* base = sm + cur * 16384;
    half8 af[4];
#pragma unroll
    for (int fm = 0; fm < 4; fm++)
      af[fm] = *(const half8*)(base + offA[fm]);
#pragma unroll
    for (int fn = 0; fn < 4; fn++) {
      const half8 bv = *(const half8*)(base + offB[fn]);
#pragma unroll
      for (int fm = 0; fm < 4; fm++)
        acc[fm][fn] = __builtin_amdgcn_mfma_f32_16x16x32_f16(af[fm], bv, acc[fm][fn], 0, 0, 0);
    }
    __syncthreads();
    cur ^= 1;
  }

  unsigned short* STb = ST + (size_t)batch * NN * NN;
#pragma unroll
  for (int fm = 0; fm < 4; fm++) {
#pragma unroll
    for (int q = 0; q < 4; q++) {
      const int n = m0 + mrow + fm * 16 + fg * 4 + q;
#pragma unroll
      for (int fn = 0; fn < 4; fn++) {
        const int j = n0 + ncol + fn * 16 + fr;
        STb[(size_t)n * NN + j] = f2h(acc[fm][fn][q]);
      }
    }
  }
}

// ---------------------------------------------------------------------------
// K4: fused sparse stage — ONE WAVE per (n,b) column; 4 batches per block;
// one __syncthreads. Step 1 is a single contiguous-row f16 gather from ST.
__global__ __launch_bounds__(256) void k_fused(const unsigned short* __restrict__ ST,
                                               const unsigned short* __restrict__ xt,
                                               const float* __restrict__ Wsub,
                                               const float* __restrict__ pnw,
                                               const int* __restrict__ col_idx,
                                               const int* __restrict__ col_cnt,
                                               const int* __restrict__ col_off,
                                               float* __restrict__ Att,
                                               float* __restrict__ agg) {
  // XCD-exclusive swizzle: xcd = id&7 owns batches [xcd*8, xcd*8+8).
  const int id = blockIdx.x;          // 0..8191
  const int xcd = id & 7;
  const int r = id >> 3;
  const int n = r & 511;
  const int bgrp = r >> 9;
  const int t = threadIdx.x;
  const int wave = t >> 6, lane = t & 63;
  const int b = (xcd << 3) + (bgrp << 2) + wave;

  __shared__ int   lsh[MAXC + 1];
  __shared__ int   lshB[MAXC + 1];
  __shared__ float Wsh[MAXC * MAXC];
  __shared__ float vsh[4][MAXC];
  __shared__ float ash[4][MAXC + 1];

  const int c = col_cnt[n];
  if (t < c) {
    const int v = col_idx[n * MAXC + t];
    lsh[t] = v;
    lshB[t] = v << 9;
  }
  if (t == c) { lsh[c] = n; lshB[c] = n << 9; }
  {
    const int cc = c * c;
    const float* Wp = Wsub + col_off[n];
    for (int i = t; i < cc; i += 256) Wsh[i] = Wp[i];
  }
  __syncthreads();   // the only block barrier

  // Step 1: v[ji] = ST[b][n][lsh[ji]] — one 2B load per lane from one row.
  const unsigned short* STrow = ST + ((size_t)b * NN + n) * NN;
  if (lane < c) vsh[wave][lane] = h2f(STrow[lsh[lane]]);

  // Step 2: aval[mi] = sum_ji Wsh[ji*c+mi] * v[ji]  (lane = mi)
  float aval = 0.0f;
  if (lane < c) {
    for (int ji = 0; ji < c; ji++)
      aval += Wsh[ji * c + lane] * vsh[wave][ji];
  }

  // Step 3: in-wave softmax over {aval[0..c), pnw[n] at diag, 512-c-1 zeros}
  const float dlg = pnw[n];
  float mval = (lane < c) ? aval : -INFINITY;
#pragma unroll
  for (int off = 32; off; off >>= 1) mval = fmaxf(mval, __shfl_xor(mval, off));
  const float colmax = fmaxf(mval, fmaxf(dlg, 0.0f));
  const float e = (lane < c) ? __expf(aval - colmax) : 0.0f;
  float sum = e;
#pragma unroll
  for (int off = 32; off; off >>= 1) sum += __shfl_xor(sum, off);
  const float denom = sum + __expf(dlg - colmax)
                    + (float)(NN - c - 1) * __expf(-colmax);
  const float inv = 1.0f / denom;

  // Step 4/5: Att column scatter (rest of column stays zero-filled)
  float* Acol = Att + (size_t)b * NN * NN + n;
  if (lane < c) {
    const float attv = e * inv;
    ash[wave][lane] = attv;
    Acol[(size_t)lsh[lane] * NN] = attv;
  }
  if (lane == c) {
    const float dv = __expf(dlg - colmax) * inv;
    ash[wave][c] = dv;
    Acol[(size_t)n * NN] = dv;
  }

  // Step 6: agg[b,n,:] = sum_{mi<=c} ash[mi] * xt[b,lsh[mi],:]
  const char* xtb = (const char*)(xt + (size_t)b * NN * SS);
  f32x4 acc = (f32x4)0.0f;
  for (int mi = 0; mi <= c; mi++) {
    const float a = ash[wave][mi];
    const uint2 v = *(const uint2*)(xtb + lshB[mi] + lane * 8);
    const float2 x01 = unpackh2(v.x);
    const float2 x23 = unpackh2(v.y);
    acc.x += a * x01.x;
    acc.y += a * x01.y;
    acc.z += a * x23.x;
    acc.w += a * x23.y;
  }
  *(f32x4*)(agg + ((size_t)b * NN + n) * SS + lane * 4) = acc;
}

// ---------------------------------------------------------------------------
extern "C" void kernel_launch(void* const* d_in, const int* in_sizes, int n_in,
                              void* d_out, int out_size, void* d_ws, size_t ws_size,
                              hipStream_t stream) {
  const float* x    = (const float*)d_in[0];
  const float* adj  = (const float*)d_in[1];
  const float* W    = (const float*)d_in[2];
  const float* pnw  = (const float*)d_in[3];
  const float* Wq_w = (const float*)d_in[4];
  const float* Wq_b = (const float*)d_in[5];
  const float* Wk_w = (const float*)d_in[6];
  const float* Wk_b = (const float*)d_in[7];

  float* agg = (float*)d_out;                        // (B,N,S)
  float* Att = (float*)d_out + (size_t)BB * NN * SS; // (B,N,N)

  char* p = (char*)d_ws;
  unsigned short* xp  = (unsigned short*)p; p += (size_t)BB * SS * 512 * 2;   // 16.78 MB (f16)
  unsigned short* Wqp = (unsigned short*)p; p += (size_t)NN * 512 * 2;        // 0.52 MB
  unsigned short* Wkp = (unsigned short*)p; p += (size_t)NN * 512 * 2;        // 0.52 MB
  unsigned short* Qt  = (unsigned short*)p; p += (size_t)BB * NN * SS * 2;    // 16.78 MB (f16)
  unsigned short* Kt  = (unsigned short*)p; p += (size_t)BB * NN * SS * 2;    // 16.78 MB (f16)
  unsigned short* xt  = (unsigned short*)p; p += (size_t)BB * NN * SS * 2;    // 16.78 MB (f16)
  unsigned short* ST  = (unsigned short*)p; p += (size_t)BB * NN * NN * 2;    // 33.55 MB (f16)
  float* Wsub = (float*)p; p += (size_t)NN * MAXC * MAXC * 4;                 // 8.39 MB (bound)
  int* col_idx = (int*)p; p += (size_t)NN * MAXC * 4;
  int* col_cnt = (int*)p; p += NN * 4;
  int* col_off = (int*)p;

  k_collist<<<dim3(NN / 4), dim3(256), 0, stream>>>(adj, col_idx, col_cnt);
  k_wsub<<<dim3(NN), dim3(256), 0, stream>>>(W, col_idx, col_cnt, col_off, Wsub);
  k_xprep<<<dim3(SS / 32, NN / 32, BB), dim3(32, 8), 0, stream>>>(x, xp, xt, Att);
  k_wsplit<<<dim3(NN, 2), dim3(128), 0, stream>>>(Wq_w, Wk_w, Wqp, Wkp);

  k_lin2<<<dim3(512), dim3(256), 0, stream>>>(Wqp, Wkp, Wq_b, Wk_b, xp, Qt, Kt);
  k_gram<<<dim3(1024), dim3(256), 0, stream>>>(Qt, Kt, ST);
  k_fused<<<dim3(8192), dim3(256), 0, stream>>>(ST, xt, Wsub, pnw,
                                                col_idx, col_cnt, col_off,
                                                Att, agg);
}

// Round 21
// 116.238 us; speedup vs baseline: 1.1379x; 1.0093x over previous
//
#include <hip/hip_runtime.h>
#include <hip/hip_fp16.h>
#include <cstdint>
#include <cmath>

#define BB 64
#define SS 256
#define NN 512
#define MAXC 64   // max nonzeros per adj column (mean ~25.6, true max ~46)
#define MAXC1 (MAXC + 1)

typedef float f32x4 __attribute__((ext_vector_type(4)));
typedef _Float16 half8 __attribute__((ext_vector_type(8)));

__device__ __forceinline__ unsigned short f2h(float f) {
  return __half_as_ushort(__float2half(f));
}
__device__ __forceinline__ float h2f(unsigned short u) {
  return __half2float(__ushort_as_half(u));
}
__device__ __forceinline__ float2 unpackh2(uint32_t u) {
  return make_float2(__half2float(__ushort_as_half((unsigned short)(u & 0xffffu))),
                     __half2float(__ushort_as_half((unsigned short)(u >> 16))));
}

__device__ __forceinline__ void gload_lds16(const void* g, void* s) {
  __builtin_amdgcn_global_load_lds(
      (const __attribute__((address_space(1))) uint32_t*)g,
      (__attribute__((address_space(3))) uint32_t*)s, 16, 0, 0);
}

// ---------------------------------------------------------------------------
// K0: merged {per-column adjacency lists} + {f16 weight conversion}.
// Blocks [0,128): collist, 4 columns per block (one per wave).
// Blocks [128,640): weight row conversion, n = bid-128, half-block per matrix.
__global__ __launch_bounds__(256) void k_prep0(const float* __restrict__ adj,
                                               int* __restrict__ col_idx,
                                               int* __restrict__ col_cnt,
                                               const float* __restrict__ Wq,
                                               const float* __restrict__ Wk,
                                               unsigned short* __restrict__ Wqp,
                                               unsigned short* __restrict__ Wkp) {
  if (blockIdx.x < 128) {
    const int n = blockIdx.x * 4 + (threadIdx.x >> 6);
    const int lane = threadIdx.x & 63;
    int cnt = 0;
    for (int m0 = 0; m0 < NN; m0 += 64) {
      const int m = m0 + lane;
      const float a = adj[(size_t)m * NN + n];
      unsigned long long mask = __ballot(a != 0.0f);
      const int prefix = __popcll(mask & ((1ull << lane) - 1ull));
      if (a != 0.0f && cnt + prefix < MAXC) col_idx[n * MAXC + cnt + prefix] = m;
      cnt += __popcll(mask);
    }
    if (lane == 0) col_cnt[n] = (cnt > MAXC) ? MAXC : cnt;
  } else {
    const int n = blockIdx.x - 128;
    const int half = threadIdx.x >> 7;          // 0: Wq, 1: Wk
    const float* src = half ? Wk : Wq;
    unsigned short* dst = half ? Wkp : Wqp;
    const int k = (threadIdx.x & 127) * 4;
    float4 v = *(const float4*)(src + (size_t)n * NN + k);
    ushort4 o;
    o.x = f2h(v.x); o.y = f2h(v.y); o.z = f2h(v.z); o.w = f2h(v.w);
    *(ushort4*)(dst + (size_t)n * 512 + k) = o;
  }
}

// K0b: packed W sub-blocks + per-block prefix scan. 4 waves split the ji-loop.
__global__ __launch_bounds__(256) void k_wsub(const float* __restrict__ W,
                                              const int* __restrict__ col_idx,
                                              const int* __restrict__ col_cnt,
                                              int* __restrict__ col_off,
                                              float* __restrict__ Wsub) {
  const int n = blockIdx.x;
  const int t = threadIdx.x;
  const int wave = t >> 6, lane = t & 63;
  __shared__ int lsh[MAXC];
  __shared__ int preSh;
  const int c = col_cnt[n];
  if (wave == 0) {
    int pre = 0;
#pragma unroll
    for (int i0 = 0; i0 < NN; i0 += 64) {
      const int i = i0 + lane;
      const int cc = col_cnt[i];
      pre += (i < n) ? cc * cc : 0;
    }
#pragma unroll
    for (int off = 32; off; off >>= 1) pre += __shfl_xor(pre, off);
    if (lane == 0) { col_off[n] = pre; preSh = pre; }
    if (lane < c) lsh[lane] = col_idx[n * MAXC + lane];
  }
  __syncthreads();
  if (lane < c) {
    const float* Wm = W + (size_t)lsh[lane] * NN;
    float* dst = Wsub + preSh + lane;
    for (int ji = wave; ji < c; ji += 4)
      dst[(size_t)ji * c] = Wm[lsh[ji]];
  }
}

// ---------------------------------------------------------------------------
// K1: fused x-prep: x (B,S,N) f32 -> xp (B*S,512) f16, xt (B,N,S) f16,
//     plus zero-fill of the Att output region.
__global__ __launch_bounds__(256) void k_xprep(const float* __restrict__ x,
                                               unsigned short* __restrict__ xp,
                                               unsigned short* __restrict__ xt,
                                               float* __restrict__ Att) {
  __shared__ float tile[32][33];
  const int b = blockIdx.z;
  const int s0 = blockIdx.x * 32, n0 = blockIdx.y * 32;
  const float* xb = x + (size_t)b * SS * NN;
  const int tx = threadIdx.x, ty = threadIdx.y;  // (32,8)
#pragma unroll
  for (int i = ty; i < 32; i += 8) {
    const float v = xb[(size_t)(s0 + i) * NN + n0 + tx];
    tile[i][tx] = v;
    xp[(size_t)(b * SS + s0 + i) * 512 + n0 + tx] = f2h(v);
  }
  {
    const int bid = (blockIdx.z * 16 + blockIdx.y) * 8 + blockIdx.x;
    const int t = ty * 32 + tx;
    f32x4* dst = (f32x4*)(Att + (size_t)bid * 2048);
    const f32x4 z = (f32x4)0.0f;
    dst[t] = z;
    dst[t + 256] = z;
  }
  __syncthreads();
  unsigned short* xtb = xt + (size_t)b * NN * SS;
#pragma unroll
  for (int i = ty; i < 32; i += 8)
    xtb[(size_t)(n0 + i) * SS + s0 + tx] = f2h(tile[tx][i]);
}

// ---------------------------------------------------------------------------
// K3: BOTH Linears in one block (shared X staging), 2-phase prefetch pipeline.
// Single-pass f16 GEMM (K=512 -> 16 K-steps). Q out f16, K out f16.
__global__ __launch_bounds__(256, 2) void k_lin2(const unsigned short* __restrict__ Wqp,
                                                 const unsigned short* __restrict__ Wkp,
                                                 const float* __restrict__ bq,
                                                 const float* __restrict__ bk,
                                                 const unsigned short* __restrict__ xp,
                                                 unsigned short* __restrict__ Qt,
                                                 unsigned short* __restrict__ Kt) {
  __shared__ __align__(16) char sm[49152];
  const int t = threadIdx.x;
  const int w = t >> 6, l = t & 63;
  const int id = blockIdx.x;
  const int xcd = id & 7, sub = id >> 3;
  const int bn0 = (xcd * 16 + (sub >> 2)) * 128;  // r = b*256+s
  const int bm0 = (sub & 3) * 128;                // n

  const int swz = (((l & 3) ^ ((l >> 3) & 3))) * 16;
  const char* srcb[6];
  char* dstb[6];
#pragma unroll
  for (int i = 0; i < 6; i++) {
    const int ch = w * 6 + i;
    const int panel = ch >> 3, rowgrp = ch & 7;
    const int row = rowgrp * 16 + (l >> 2);
    const char* g0 = (panel == 0) ? (const char*)Wqp
                   : (panel == 1) ? (const char*)Wkp : (const char*)xp;
    const int gr = ((panel == 2) ? bn0 : bm0) + row;
    srcb[i] = g0 + (size_t)gr * 1024 + swz;
    dstb[i] = sm + panel * 8192 + rowgrp * 1024 + l * 16;
  }

  const int fr = l & 15, fg = l >> 4;
  const int mrow = (w >> 1) * 64, ncol = (w & 1) * 64;
  const int slot = (fg ^ ((fr >> 1) & 3)) * 16;
  int offQ[4], offK[4], offB[4];
#pragma unroll
  for (int fm = 0; fm < 4; fm++) {
    offQ[fm] = (mrow + fm * 16 + fr) * 64 + slot;
    offK[fm] = 8192 + (mrow + fm * 16 + fr) * 64 + slot;
    offB[fm] = 16384 + (ncol + fm * 16 + fr) * 64 + slot;
  }

  f32x4 accq[4][4], acck[4][4];
#pragma unroll
  for (int i = 0; i < 4; i++)
#pragma unroll
    for (int j = 0; j < 4; j++) { accq[i][j] = (f32x4)0.0f; acck[i][j] = (f32x4)0.0f; }

#pragma unroll
  for (int i = 0; i < 6; i++) gload_lds16(srcb[i], dstb[i]);
  __syncthreads();

  int cur = 0;
  for (int kk = 0; kk < 16; kk++) {
    if (kk + 1 < 16) {
      const int ko = (kk + 1) * 64;
      const int boff = (cur ^ 1) * 24576;
#pragma unroll
      for (int i = 0; i < 6; i++)
        gload_lds16(srcb[i] + ko, dstb[i] + boff);
    }
    const char* base = sm + cur * 24576;
    half8 afq[4], afk[4];
#pragma unroll
    for (int fm = 0; fm < 4; fm++) {
      afq[fm] = *(const half8*)(base + offQ[fm]);
      afk[fm] = *(const half8*)(base + offK[fm]);
    }
#pragma unroll
    for (int fn = 0; fn < 4; fn++) {
      const half8 bv = *(const half8*)(base + offB[fn]);
#pragma unroll
      for (int fm = 0; fm < 4; fm++) {
        accq[fm][fn] = __builtin_amdgcn_mfma_f32_16x16x32_f16(afq[fm], bv, accq[fm][fn], 0, 0, 0);
        acck[fm][fn] = __builtin_amdgcn_mfma_f32_16x16x32_f16(afk[fm], bv, acck[fm][fn], 0, 0, 0);
      }
    }
    __syncthreads();
    cur ^= 1;
  }

  // epilogue: D col = lane&15 (-> r), row = (lane>>4)*4+q (-> n)
  const int b = bn0 >> 8;
  const int sbase = (bn0 & 255) + ncol;
#pragma unroll
  for (int fm = 0; fm < 4; fm++) {
#pragma unroll
    for (int q = 0; q < 4; q++) {
      const int n = bm0 + mrow + fm * 16 + fg * 4 + q;
      const float bvq = bq[n];
      const float bvk = bk[n];
#pragma unroll
      for (int fn = 0; fn < 4; fn++) {
        const int s = sbase + fn * 16 + fr;
        Qt[((size_t)b * NN + n) * SS + s] = f2h(accq[fm][fn][q] + bvq);
        Kt[((size_t)b * NN + n) * SS + s] = f2h(acck[fm][fn][q] + bvk);
      }
    }
  }
}

// ---------------------------------------------------------------------------
// K3b: dense Gram per batch: ST[b][n][j] = <Q[b,n,:], K[b,j,:]>, f16 out.
__global__ __launch_bounds__(256, 2) void k_gram(const unsigned short* __restrict__ Qt,
                                                 const unsigned short* __restrict__ Kt,
                                                 unsigned short* __restrict__ ST) {
  __shared__ __align__(16) char sm[32768];
  const int t = threadIdx.x;
  const int w = t >> 6, l = t & 63;
  const int id = blockIdx.x;
  const int xcd = id & 7, rest = id >> 3;       // rest 0..127
  const int batch = (xcd << 3) + (rest >> 4);
  const int tile = rest & 15;
  const int m0 = (tile >> 2) * 128;             // n rows (A = Q)
  const int n0 = (tile & 3) * 128;              // j rows (B = K)

  const int swz = (((l & 3) ^ ((l >> 3) & 3))) * 16;
  const char* srcb[4];
  char* dstb[4];
#pragma unroll
  for (int i = 0; i < 4; i++) {
    const int ch = w * 4 + i;                   // 16 chunks: A(0..7), B(8..15)
    const int panel = ch >> 3, rowgrp = ch & 7;
    const int row = rowgrp * 16 + (l >> 2);
    const char* g0 = panel ? (const char*)Kt : (const char*)Qt;
    const int gr = (panel ? n0 : m0) + row;
    srcb[i] = g0 + ((size_t)batch * 512 + gr) * 512 + swz;
    dstb[i] = sm + panel * 8192 + rowgrp * 1024 + l * 16;
  }

  const int fr = l & 15, fg = l >> 4;
  const int mrow = (w >> 1) * 64, ncol = (w & 1) * 64;
  const int slot = (fg ^ ((fr >> 1) & 3)) * 16;
  int offA[4], offB[4];
#pragma unroll
  for (int fm = 0; fm < 4; fm++) {
    offA[fm] = (mrow + fm * 16 + fr) * 64 + slot;
    offB[fm] = 8192 + (ncol + fm * 16 + fr) * 64 + slot;
  }

  f32x4 acc[4][4];
#pragma unroll
  for (int i = 0; i < 4; i++)
#pragma unroll
    for (int j = 0; j < 4; j++) acc[i][j] = (f32x4)0.0f;

#pragma unroll
  for (int i = 0; i < 4; i++) gload_lds16(srcb[i], dstb[i]);
  __syncthreads();

  int cur = 0;
  for (int kk = 0; kk < 8; kk++) {
    if (kk + 1 < 8) {
      const int ko = (kk + 1) * 64;
      const int boff = (cur ^ 1) * 16384;
#pragma unroll
      for (int i = 0; i < 4; i++)
        gload_lds16(srcb[i] + ko, dstb[i] + boff);
    }
    const char* base = sm + cur * 16384;
    half8 af[4];
#pragma unroll
    for (int fm = 0; fm < 4; fm++)
      af[fm] = *(const half8*)(base + offA[fm]);
#pragma unroll
    for (int fn = 0; fn < 4; fn++) {
      const half8 bv = *(const half8*)(base + offB[fn]);
#pragma unroll
      for (int fm = 0; fm < 4; fm++)
        acc[fm][fn] = __builtin_amdgcn_mfma_f32_16x16x32_f16(af[fm], bv, acc[fm][fn], 0, 0, 0);
    }
    __syncthreads();
    cur ^= 1;
  }

  unsigned short* STb = ST + (size_t)batch * NN * NN;
#pragma unroll
  for (int fm = 0; fm < 4; fm++) {
#pragma unroll
    for (int q = 0; q < 4; q++) {
      const int n = m0 + mrow + fm * 16 + fg * 4 + q;
#pragma unroll
      for (int fn = 0; fn < 4; fn++) {
        const int j = n0 + ncol + fn * 16 + fr;
        STb[(size_t)n * NN + j] = f2h(acc[fm][fn][q]);
      }
    }
  }
}

// ---------------------------------------------------------------------------
// K4: fused sparse stage — ONE WAVE per (n,b) column; 4 batches per block;
// one __syncthreads. The ST gather is issued per-wave BEFORE the cooperative
// Wsub staging + barrier so its latency hides under the stage (R21 change).
__global__ __launch_bounds__(256) void k_fused(const unsigned short* __restrict__ ST,
                                               const unsigned short* __restrict__ xt,
                                               const float* __restrict__ Wsub,
                                               const float* __restrict__ pnw,
                                               const int* __restrict__ col_idx,
                                               const int* __restrict__ col_cnt,
                                               const int* __restrict__ col_off,
                                               float* __restrict__ Att,
                                               float* __restrict__ agg) {
  // XCD-exclusive swizzle: xcd = id&7 owns batches [xcd*8, xcd*8+8).
  const int id = blockIdx.x;          // 0..8191
  const int xcd = id & 7;
  const int r = id >> 3;
  const int n = r & 511;
  const int bgrp = r >> 9;
  const int t = threadIdx.x;
  const int wave = t >> 6, lane = t & 63;
  const int b = (xcd << 3) + (bgrp << 2) + wave;

  __shared__ int   lsh[MAXC + 1];
  __shared__ int   lshB[MAXC + 1];
  __shared__ float Wsh[MAXC * MAXC];
  __shared__ float vsh[4][MAXC];
  __shared__ float ash[4][MAXC + 1];

  const int c = col_cnt[n];

  // Early per-wave gather: each wave loads its col_idx slice (L2-broadcast)
  // and issues the scattered ST read immediately.
  unsigned short stv = 0;
  if (lane < c) {
    const int myIdx = col_idx[n * MAXC + lane];
    stv = ST[((size_t)b * NN + n) * NN + myIdx];
  }

  // Cooperative (block-wide) setup overlapping the gather above.
  if (t < c) {
    const int v = col_idx[n * MAXC + t];
    lsh[t] = v;
    lshB[t] = v << 9;
  }
  if (t == c) { lsh[c] = n; lshB[c] = n << 9; }
  {
    const int cc = c * c;
    const float* Wp = Wsub + col_off[n];
    for (int i = t; i < cc; i += 256) Wsh[i] = Wp[i];
  }
  __syncthreads();   // the only block barrier

  // Step 1: publish gathered v to LDS (same-wave write/read, in-order DS).
  if (lane < c) vsh[wave][lane] = h2f(stv);

  // Step 2: aval[mi] = sum_ji Wsh[ji*c+mi] * v[ji]  (lane = mi)
  float aval = 0.0f;
  if (lane < c) {
    for (int ji = 0; ji < c; ji++)
      aval += Wsh[ji * c + lane] * vsh[wave][ji];
  }

  // Step 3: in-wave softmax over {aval[0..c), pnw[n] at diag, 512-c-1 zeros}
  const float dlg = pnw[n];
  float mval = (lane < c) ? aval : -INFINITY;
#pragma unroll
  for (int off = 32; off; off >>= 1) mval = fmaxf(mval, __shfl_xor(mval, off));
  const float colmax = fmaxf(mval, fmaxf(dlg, 0.0f));
  const float e = (lane < c) ? __expf(aval - colmax) : 0.0f;
  float sum = e;
#pragma unroll
  for (int off = 32; off; off >>= 1) sum += __shfl_xor(sum, off);
  const float denom = sum + __expf(dlg - colmax)
                    + (float)(NN - c - 1) * __expf(-colmax);
  const float inv = 1.0f / denom;

  // Step 4/5: Att column scatter (rest of column stays zero-filled)
  float* Acol = Att + (size_t)b * NN * NN + n;
  if (lane < c) {
    const float attv = e * inv;
    ash[wave][lane] = attv;
    Acol[(size_t)lsh[lane] * NN] = attv;
  }
  if (lane == c) {
    const float dv = __expf(dlg - colmax) * inv;
    ash[wave][c] = dv;
    Acol[(size_t)n * NN] = dv;
  }

  // Step 6: agg[b,n,:] = sum_{mi<=c} ash[mi] * xt[b,lsh[mi],:]
  const char* xtb = (const char*)(xt + (size_t)b * NN * SS);
  f32x4 acc = (f32x4)0.0f;
  for (int mi = 0; mi <= c; mi++) {
    const float a = ash[wave][mi];
    const uint2 v = *(const uint2*)(xtb + lshB[mi] + lane * 8);
    const float2 x01 = unpackh2(v.x);
    const float2 x23 = unpackh2(v.y);
    acc.x += a * x01.x;
    acc.y += a * x01.y;
    acc.z += a * x23.x;
    acc.w += a * x23.y;
  }
  *(f32x4*)(agg + ((size_t)b * NN + n) * SS + lane * 4) = acc;
}

// ---------------------------------------------------------------------------
extern "C" void kernel_launch(void* const* d_in, const int* in_sizes, int n_in,
                              void* d_out, int out_size, void* d_ws, size_t ws_size,
                              hipStream_t stream) {
  const float* x    = (const float*)d_in[0];
  const float* adj  = (const float*)d_in[1];
  const float* W    = (const float*)d_in[2];
  const float* pnw  = (const float*)d_in[3];
  const float* Wq_w = (const float*)d_in[4];
  const float* Wq_b = (const float*)d_in[5];
  const float* Wk_w = (const float*)d_in[6];
  const float* Wk_b = (const float*)d_in[7];

  float* agg = (float*)d_out;                        // (B,N,S)
  float* Att = (float*)d_out + (size_t)BB * NN * SS; // (B,N,N)

  char* p = (char*)d_ws;
  unsigned short* xp  = (unsigned short*)p; p += (size_t)BB * SS * 512 * 2;   // 16.78 MB (f16)
  unsigned short* Wqp = (unsigned short*)p; p += (size_t)NN * 512 * 2;        // 0.52 MB
  unsigned short* Wkp = (unsigned short*)p; p += (size_t)NN * 512 * 2;        // 0.52 MB
  unsigned short* Qt  = (unsigned short*)p; p += (size_t)BB * NN * SS * 2;    // 16.78 MB (f16)
  unsigned short* Kt  = (unsigned short*)p; p += (size_t)BB * NN * SS * 2;    // 16.78 MB (f16)
  unsigned short* xt  = (unsigned short*)p; p += (size_t)BB * NN * SS * 2;    // 16.78 MB (f16)
  unsigned short* ST  = (unsigned short*)p; p += (size_t)BB * NN * NN * 2;    // 33.55 MB (f16)
  float* Wsub = (float*)p; p += (size_t)NN * MAXC * MAXC * 4;                 // 8.39 MB (bound)
  int* col_idx = (int*)p; p += (size_t)NN * MAXC * 4;
  int* col_cnt = (int*)p; p += NN * 4;
  int* col_off = (int*)p;

  k_prep0<<<dim3(640), dim3(256), 0, stream>>>(adj, col_idx, col_cnt,
                                               Wq_w, Wk_w, Wqp, Wkp);
  k_wsub<<<dim3(NN), dim3(256), 0, stream>>>(W, col_idx, col_cnt, col_off, Wsub);
  k_xprep<<<dim3(SS / 32, NN / 32, BB), dim3(32, 8), 0, stream>>>(x, xp, xt, Att);

  k_lin2<<<dim3(512), dim3(256), 0, stream>>>(Wqp, Wkp, Wq_b, Wk_b, xp, Qt, Kt);
  k_gram<<<dim3(1024), dim3(256), 0, stream>>>(Qt, Kt, ST);
  k_fused<<<dim3(8192), dim3(256), 0, stream>>>(ST, xt, Wsub, pnw,
                                                col_idx, col_cnt, col_off,
                                                Att, agg);
}

// Round 22
// 111.262 us; speedup vs baseline: 1.1887x; 1.0447x over previous
//
#include <hip/hip_runtime.h>
#include <hip/hip_fp16.h>
#include <cstdint>
#include <cmath>

#define BB 64
#define SS 256
#define NN 512
#define MAXC 64   // max nonzeros per adj column (mean ~25.6, true max ~46)

typedef float f32x4 __attribute__((ext_vector_type(4)));
typedef _Float16 half8 __attribute__((ext_vector_type(8)));

__device__ __forceinline__ unsigned short f2h(float f) {
  return __half_as_ushort(__float2half(f));
}
__device__ __forceinline__ float h2f(unsigned short u) {
  return __half2float(__ushort_as_half(u));
}

__device__ __forceinline__ void gload_lds16(const void* g, void* s) {
  __builtin_amdgcn_global_load_lds(
      (const __attribute__((address_space(1))) uint32_t*)g,
      (__attribute__((address_space(3))) uint32_t*)s, 16, 0, 0);
}

// ---------------------------------------------------------------------------
// K0: merged {per-column adjacency lists} + {f16 weight conversion}.
__global__ __launch_bounds__(256) void k_prep0(const float* __restrict__ adj,
                                               int* __restrict__ col_idx,
                                               int* __restrict__ col_cnt,
                                               const float* __restrict__ Wq,
                                               const float* __restrict__ Wk,
                                               unsigned short* __restrict__ Wqp,
                                               unsigned short* __restrict__ Wkp) {
  if (blockIdx.x < 128) {
    const int n = blockIdx.x * 4 + (threadIdx.x >> 6);
    const int lane = threadIdx.x & 63;
    int cnt = 0;
    for (int m0 = 0; m0 < NN; m0 += 64) {
      const int m = m0 + lane;
      const float a = adj[(size_t)m * NN + n];
      unsigned long long mask = __ballot(a != 0.0f);
      const int prefix = __popcll(mask & ((1ull << lane) - 1ull));
      if (a != 0.0f && cnt + prefix < MAXC) col_idx[n * MAXC + cnt + prefix] = m;
      cnt += __popcll(mask);
    }
    if (lane == 0) col_cnt[n] = (cnt > MAXC) ? MAXC : cnt;
  } else {
    const int n = blockIdx.x - 128;
    const int half = threadIdx.x >> 7;          // 0: Wq, 1: Wk
    const float* src = half ? Wk : Wq;
    unsigned short* dst = half ? Wkp : Wqp;
    const int k = (threadIdx.x & 127) * 4;
    float4 v = *(const float4*)(src + (size_t)n * NN + k);
    ushort4 o;
    o.x = f2h(v.x); o.y = f2h(v.y); o.z = f2h(v.z); o.w = f2h(v.w);
    *(ushort4*)(dst + (size_t)n * 512 + k) = o;
  }
}

// K0b: packed W sub-blocks + per-block prefix scan. 4 waves split the ji-loop.
__global__ __launch_bounds__(256) void k_wsub(const float* __restrict__ W,
                                              const int* __restrict__ col_idx,
                                              const int* __restrict__ col_cnt,
                                              int* __restrict__ col_off,
                                              float* __restrict__ Wsub) {
  const int n = blockIdx.x;
  const int t = threadIdx.x;
  const int wave = t >> 6, lane = t & 63;
  __shared__ int lsh[MAXC];
  __shared__ int preSh;
  const int c = col_cnt[n];
  if (wave == 0) {
    int pre = 0;
#pragma unroll
    for (int i0 = 0; i0 < NN; i0 += 64) {
      const int i = i0 + lane;
      const int cc = col_cnt[i];
      pre += (i < n) ? cc * cc : 0;
    }
#pragma unroll
    for (int off = 32; off; off >>= 1) pre += __shfl_xor(pre, off);
    if (lane == 0) { col_off[n] = pre; preSh = pre; }
    if (lane < c) lsh[lane] = col_idx[n * MAXC + lane];
  }
  __syncthreads();
  if (lane < c) {
    const float* Wm = W + (size_t)lsh[lane] * NN;
    float* dst = Wsub + preSh + lane;
    for (int ji = wave; ji < c; ji += 4)
      dst[(size_t)ji * c] = Wm[lsh[ji]];
  }
}

// ---------------------------------------------------------------------------
// K1: x (B,S,N) f32 -> xp (B*S,512) f16, plus zero-fill of Att output region.
// No transpose needed anymore (agg is computed by dense GEMM from xp).
__global__ __launch_bounds__(256) void k_xprep(const float* __restrict__ x,
                                               unsigned short* __restrict__ xp,
                                               float* __restrict__ Att) {
  const int t = threadIdx.x;
  const size_t base = ((size_t)blockIdx.x * 256 + t) * 4;
  float4 v = *(const float4*)(x + base);
  ushort4 o;
  o.x = f2h(v.x); o.y = f2h(v.y); o.z = f2h(v.z); o.w = f2h(v.w);
  *(ushort4*)(xp + base) = o;
  f32x4* dst = (f32x4*)(Att + (size_t)blockIdx.x * 2048);
  const f32x4 z = (f32x4)0.0f;
  dst[t] = z;
  dst[t + 256] = z;
}

// ---------------------------------------------------------------------------
// K3: BOTH Linears in one block (shared X staging), 2-phase prefetch pipeline.
// Single-pass f16 GEMM (K=512 -> 16 K-steps). Q out f16, K out f16.
__global__ __launch_bounds__(256, 2) void k_lin2(const unsigned short* __restrict__ Wqp,
                                                 const unsigned short* __restrict__ Wkp,
                                                 const float* __restrict__ bq,
                                                 const float* __restrict__ bk,
                                                 const unsigned short* __restrict__ xp,
                                                 unsigned short* __restrict__ Qt,
                                                 unsigned short* __restrict__ Kt) {
  __shared__ __align__(16) char sm[49152];
  const int t = threadIdx.x;
  const int w = t >> 6, l = t & 63;
  const int id = blockIdx.x;
  const int xcd = id & 7, sub = id >> 3;
  const int bn0 = (xcd * 16 + (sub >> 2)) * 128;  // r = b*256+s
  const int bm0 = (sub & 3) * 128;                // n

  const int swz = (((l & 3) ^ ((l >> 3) & 3))) * 16;
  const char* srcb[6];
  char* dstb[6];
#pragma unroll
  for (int i = 0; i < 6; i++) {
    const int ch = w * 6 + i;
    const int panel = ch >> 3, rowgrp = ch & 7;
    const int row = rowgrp * 16 + (l >> 2);
    const char* g0 = (panel == 0) ? (const char*)Wqp
                   : (panel == 1) ? (const char*)Wkp : (const char*)xp;
    const int gr = ((panel == 2) ? bn0 : bm0) + row;
    srcb[i] = g0 + (size_t)gr * 1024 + swz;
    dstb[i] = sm + panel * 8192 + rowgrp * 1024 + l * 16;
  }

  const int fr = l & 15, fg = l >> 4;
  const int mrow = (w >> 1) * 64, ncol = (w & 1) * 64;
  const int slot = (fg ^ ((fr >> 1) & 3)) * 16;
  int offQ[4], offK[4], offB[4];
#pragma unroll
  for (int fm = 0; fm < 4; fm++) {
    offQ[fm] = (mrow + fm * 16 + fr) * 64 + slot;
    offK[fm] = 8192 + (mrow + fm * 16 + fr) * 64 + slot;
    offB[fm] = 16384 + (ncol + fm * 16 + fr) * 64 + slot;
  }

  f32x4 accq[4][4], acck[4][4];
#pragma unroll
  for (int i = 0; i < 4; i++)
#pragma unroll
    for (int j = 0; j < 4; j++) { accq[i][j] = (f32x4)0.0f; acck[i][j] = (f32x4)0.0f; }

#pragma unroll
  for (int i = 0; i < 6; i++) gload_lds16(srcb[i], dstb[i]);
  __syncthreads();

  int cur = 0;
  for (int kk = 0; kk < 16; kk++) {
    if (kk + 1 < 16) {
      const int ko = (kk + 1) * 64;
      const int boff = (cur ^ 1) * 24576;
#pragma unroll
      for (int i = 0; i < 6; i++)
        gload_lds16(srcb[i] + ko, dstb[i] + boff);
    }
    const char* base = sm + cur * 24576;
    half8 afq[4], afk[4];
#pragma unroll
    for (int fm = 0; fm < 4; fm++) {
      afq[fm] = *(const half8*)(base + offQ[fm]);
      afk[fm] = *(const half8*)(base + offK[fm]);
    }
#pragma unroll
    for (int fn = 0; fn < 4; fn++) {
      const half8 bv = *(const half8*)(base + offB[fn]);
#pragma unroll
      for (int fm = 0; fm < 4; fm++) {
        accq[fm][fn] = __builtin_amdgcn_mfma_f32_16x16x32_f16(afq[fm], bv, accq[fm][fn], 0, 0, 0);
        acck[fm][fn] = __builtin_amdgcn_mfma_f32_16x16x32_f16(afk[fm], bv, acck[fm][fn], 0, 0, 0);
      }
    }
    __syncthreads();
    cur ^= 1;
  }

  // epilogue: D col = lane&15 (-> r), row = (lane>>4)*4+q (-> n)
  const int b = bn0 >> 8;
  const int sbase = (bn0 & 255) + ncol;
#pragma unroll
  for (int fm = 0; fm < 4; fm++) {
#pragma unroll
    for (int q = 0; q < 4; q++) {
      const int n = bm0 + mrow + fm * 16 + fg * 4 + q;
      const float bvq = bq[n];
      const float bvk = bk[n];
#pragma unroll
      for (int fn = 0; fn < 4; fn++) {
        const int s = sbase + fn * 16 + fr;
        Qt[((size_t)b * NN + n) * SS + s] = f2h(accq[fm][fn][q] + bvq);
        Kt[((size_t)b * NN + n) * SS + s] = f2h(acck[fm][fn][q] + bvk);
      }
    }
  }
}

// ---------------------------------------------------------------------------
// K3b: dense Gram per batch: ST[b][n][j] = <Q[b,n,:], K[b,j,:]>, f16 out.
__global__ __launch_bounds__(256, 2) void k_gram(const unsigned short* __restrict__ Qt,
                                                 const unsigned short* __restrict__ Kt,
                                                 unsigned short* __restrict__ ST) {
  __shared__ __align__(16) char sm[32768];
  const int t = threadIdx.x;
  const int w = t >> 6, l = t & 63;
  const int id = blockIdx.x;
  const int xcd = id & 7, rest = id >> 3;       // rest 0..127
  const int batch = (xcd << 3) + (rest >> 4);
  const int tile = rest & 15;
  const int m0 = (tile >> 2) * 128;             // n rows (A = Q)
  const int n0 = (tile & 3) * 128;              // j rows (B = K)

  const int swz = (((l & 3) ^ ((l >> 3) & 3))) * 16;
  const char* srcb[4];
  char* dstb[4];
#pragma unroll
  for (int i = 0; i < 4; i++) {
    const int ch = w * 4 + i;                   // 16 chunks: A(0..7), B(8..15)
    const int panel = ch >> 3, rowgrp = ch & 7;
    const int row = rowgrp * 16 + (l >> 2);
    const char* g0 = panel ? (const char*)Kt : (const char*)Qt;
    const int gr = (panel ? n0 : m0) + row;
    srcb[i] = g0 + ((size_t)batch * 512 + gr) * 512 + swz;
    dstb[i] = sm + panel * 8192 + rowgrp * 1024 + l * 16;
  }

  const int fr = l & 15, fg = l >> 4;
  const int mrow = (w >> 1) * 64, ncol = (w & 1) * 64;
  const int slot = (fg ^ ((fr >> 1) & 3)) * 16;
  int offA[4], offB[4];
#pragma unroll
  for (int fm = 0; fm < 4; fm++) {
    offA[fm] = (mrow + fm * 16 + fr) * 64 + slot;
    offB[fm] = 8192 + (ncol + fm * 16 + fr) * 64 + slot;
  }

  f32x4 acc[4][4];
#pragma unroll
  for (int i = 0; i < 4; i++)
#pragma unroll
    for (int j = 0; j < 4; j++) acc[i][j] = (f32x4)0.0f;

#pragma unroll
  for (int i = 0; i < 4; i++) gload_lds16(srcb[i], dstb[i]);
  __syncthreads();

  int cur = 0;
  for (int kk = 0; kk < 8; kk++) {
    if (kk + 1 < 8) {
      const int ko = (kk + 1) * 64;
      const int boff = (cur ^ 1) * 16384;
#pragma unroll
      for (int i = 0; i < 4; i++)
        gload_lds16(srcb[i] + ko, dstb[i] + boff);
    }
    const char* base = sm + cur * 16384;
    half8 af[4];
#pragma unroll
    for (int fm = 0; fm < 4; fm++)
      af[fm] = *(const half8*)(base + offA[fm]);
#pragma unroll
    for (int fn = 0; fn < 4; fn++) {
      const half8 bv = *(const half8*)(base + offB[fn]);
#pragma unroll
      for (int fm = 0; fm < 4; fm++)
        acc[fm][fn] = __builtin_amdgcn_mfma_f32_16x16x32_f16(af[fm], bv, acc[fm][fn], 0, 0, 0);
    }
    __syncthreads();
    cur ^= 1;
  }

  unsigned short* STb = ST + (size_t)batch * NN * NN;
#pragma unroll
  for (int fm = 0; fm < 4; fm++) {
#pragma unroll
    for (int q = 0; q < 4; q++) {
      const int n = m0 + mrow + fm * 16 + fg * 4 + q;
#pragma unroll
      for (int fn = 0; fn < 4; fn++) {
        const int j = n0 + ncol + fn * 16 + fr;
        STb[(size_t)n * NN + j] = f2h(acc[fm][fn][q]);
      }
    }
  }
}

// ---------------------------------------------------------------------------
// K4: fused sparse stage — ONE WAVE per (n,b) column; 4 batches per block.
// Outputs: f32 Att column scatter (d_out) AND dense f16 row Att2[b][n][:]
// (Att^T layout, built in a ushort-only LDS buffer -> single-type DS accesses).
__global__ __launch_bounds__(256) void k_fused(const unsigned short* __restrict__ ST,
                                               const float* __restrict__ Wsub,
                                               const float* __restrict__ pnw,
                                               const int* __restrict__ col_idx,
                                               const int* __restrict__ col_cnt,
                                               const int* __restrict__ col_off,
                                               float* __restrict__ Att,
                                               unsigned short* __restrict__ Att2) {
  const int id = blockIdx.x;          // 0..8191
  const int xcd = id & 7;
  const int r = id >> 3;
  const int n = r & 511;
  const int bgrp = r >> 9;
  const int t = threadIdx.x;
  const int wave = t >> 6, lane = t & 63;
  const int b = (xcd << 3) + (bgrp << 2) + wave;

  __shared__ int   lsh[MAXC + 1];
  __shared__ float Wsh[MAXC * MAXC];
  __shared__ float vsh[4][MAXC];
  __shared__ unsigned short ush[4][NN];   // dense Att^T row build (ushort-only)

  const int c = col_cnt[n];

  // Early per-wave ST gather (hides under the cooperative staging below).
  unsigned short stv = 0;
  if (lane < c) {
    const int myIdx = col_idx[n * MAXC + lane];
    stv = ST[((size_t)b * NN + n) * NN + myIdx];
  }

  // Zero this wave's dense row (wave-private region; ushort stores only).
#pragma unroll
  for (int j = 0; j < 8; j++) ush[wave][lane * 8 + j] = 0;

  if (t < c) lsh[t] = col_idx[n * MAXC + t];
  if (t == c) lsh[c] = n;
  {
    const int cc = c * c;
    const float* Wp = Wsub + col_off[n];
    for (int i = t; i < cc; i += 256) Wsh[i] = Wp[i];
  }
  __syncthreads();   // the only block barrier

  // Step 1: publish gathered v to LDS (same-wave write/read, in-order DS).
  if (lane < c) vsh[wave][lane] = h2f(stv);

  // Step 2: aval[mi] = sum_ji Wsh[ji*c+mi] * v[ji]  (lane = mi)
  float aval = 0.0f;
  if (lane < c) {
    for (int ji = 0; ji < c; ji++)
      aval += Wsh[ji * c + lane] * vsh[wave][ji];
  }

  // Step 3: in-wave softmax over {aval[0..c), pnw[n] at diag, 512-c-1 zeros}
  const float dlg = pnw[n];
  float mval = (lane < c) ? aval : -INFINITY;
#pragma unroll
  for (int off = 32; off; off >>= 1) mval = fmaxf(mval, __shfl_xor(mval, off));
  const float colmax = fmaxf(mval, fmaxf(dlg, 0.0f));
  const float e = (lane < c) ? __expf(aval - colmax) : 0.0f;
  float sum = e;
#pragma unroll
  for (int off = 32; off; off >>= 1) sum += __shfl_xor(sum, off);
  const float denom = sum + __expf(dlg - colmax)
                    + (float)(NN - c - 1) * __expf(-colmax);
  const float inv = 1.0f / denom;

  // Step 4/5: f32 Att scatter (output) + f16 scatter into the LDS dense row.
  float* Acol = Att + (size_t)b * NN * NN + n;
  if (lane < c) {
    const float attv = e * inv;
    Acol[(size_t)lsh[lane] * NN] = attv;
    ush[wave][lsh[lane]] = f2h(attv);
  }
  if (lane == c) {
    const float dv = __expf(dlg - colmax) * inv;
    Acol[(size_t)n * NN] = dv;
    ush[wave][n] = f2h(dv);
  }

  // Dense row writeback: pack 8 ushorts/lane -> one 16B store (1KB/row).
  // Same-wave, same-type DS accesses -> in-order, no barrier needed.
  uint32_t pk[4];
#pragma unroll
  for (int j = 0; j < 4; j++) {
    const uint32_t lo = ush[wave][lane * 8 + j * 2];
    const uint32_t hi = ush[wave][lane * 8 + j * 2 + 1];
    pk[j] = lo | (hi << 16);
  }
  uint4 o = make_uint4(pk[0], pk[1], pk[2], pk[3]);
  *(uint4*)((char*)Att2 + ((size_t)b * NN + n) * 1024 + lane * 16) = o;
}

// ---------------------------------------------------------------------------
// K5: dense agg GEMM per batch: agg[b,n,s] = sum_m Att2[b][n][m] * xp[b,s][m].
// NT f16 GEMM, M=512, N=256, K=512; 128x128 tile, BK=32, 2-phase prefetch.
__global__ __launch_bounds__(256, 2) void k_agg(const unsigned short* __restrict__ Att2,
                                                const unsigned short* __restrict__ xp,
                                                float* __restrict__ agg) {
  __shared__ __align__(16) char sm[32768];
  const int t = threadIdx.x;
  const int w = t >> 6, l = t & 63;
  const int id = blockIdx.x;                    // 0..511
  const int xcd = id & 7, rest = id >> 3;       // rest 0..63
  const int batch = (xcd << 3) + (rest >> 3);   // 8 batches per XCD
  const int tile = rest & 7;
  const int m0 = (tile >> 1) * 128;             // n rows (A = Att2)
  const int s0 = (tile & 1) * 128;              // s rows (B = xp)

  const int swz = (((l & 3) ^ ((l >> 3) & 3))) * 16;
  const char* srcb[4];
  char* dstb[4];
#pragma unroll
  for (int i = 0; i < 4; i++) {
    const int ch = w * 4 + i;                   // 16 chunks: A(0..7), B(8..15)
    const int panel = ch >> 3, rowgrp = ch & 7;
    const int row = rowgrp * 16 + (l >> 2);
    const char* g0 = panel ? (const char*)xp : (const char*)Att2;
    const size_t gr = panel ? ((size_t)batch * SS + s0 + row)
                            : ((size_t)batch * NN + m0 + row);
    srcb[i] = g0 + gr * 1024 + swz;
    dstb[i] = sm + panel * 8192 + rowgrp * 1024 + l * 16;
  }

  const int fr = l & 15, fg = l >> 4;
  const int mrow = (w >> 1) * 64, ncol = (w & 1) * 64;
  const int slot = (fg ^ ((fr >> 1) & 3)) * 16;
  int offA[4], offB[4];
#pragma unroll
  for (int fm = 0; fm < 4; fm++) {
    offA[fm] = (mrow + fm * 16 + fr) * 64 + slot;
    offB[fm] = 8192 + (ncol + fm * 16 + fr) * 64 + slot;
  }

  f32x4 acc[4][4];
#pragma unroll
  for (int i = 0; i < 4; i++)
#pragma unroll
    for (int j = 0; j < 4; j++) acc[i][j] = (f32x4)0.0f;

#pragma unroll
  for (int i = 0; i < 4; i++) gload_lds16(srcb[i], dstb[i]);
  __syncthreads();

  int cur = 0;
  for (int kk = 0; kk < 16; kk++) {
    if (kk + 1 < 16) {
      const int ko = (kk + 1) * 64;
      const int boff = (cur ^ 1) * 16384;
#pragma unroll
      for (int i = 0; i < 4; i++)
        gload_lds16(srcb[i] + ko, dstb[i] + boff);
    }
    const char* base = sm + cur * 16384;
    half8 af[4];
#pragma unroll
    for (int fm = 0; fm < 4; fm++)
      af[fm] = *(const half8*)(base + offA[fm]);
#pragma unroll
    for (int fn = 0; fn < 4; fn++) {
      const half8 bv = *(const half8*)(base + offB[fn]);
#pragma unroll
      for (int fm = 0; fm < 4; fm++)
        acc[fm][fn] = __builtin_amdgcn_mfma_f32_16x16x32_f16(af[fm], bv, acc[fm][fn], 0, 0, 0);
    }
    __syncthreads();
    cur ^= 1;
  }

  // epilogue: D row -> n (A rows), D col -> s (B rows); agg (B,N,S) f32
  float* ab = agg + (size_t)batch * NN * SS;
#pragma unroll
  for (int fm = 0; fm < 4; fm++) {
#pragma unroll
    for (int q = 0; q < 4; q++) {
      const int n = m0 + mrow + fm * 16 + fg * 4 + q;
#pragma unroll
      for (int fn = 0; fn < 4; fn++) {
        const int s = s0 + ncol + fn * 16 + fr;
        ab[(size_t)n * SS + s] = acc[fm][fn][q];
      }
    }
  }
}

// ---------------------------------------------------------------------------
extern "C" void kernel_launch(void* const* d_in, const int* in_sizes, int n_in,
                              void* d_out, int out_size, void* d_ws, size_t ws_size,
                              hipStream_t stream) {
  const float* x    = (const float*)d_in[0];
  const float* adj  = (const float*)d_in[1];
  const float* W    = (const float*)d_in[2];
  const float* pnw  = (const float*)d_in[3];
  const float* Wq_w = (const float*)d_in[4];
  const float* Wq_b = (const float*)d_in[5];
  const float* Wk_w = (const float*)d_in[6];
  const float* Wk_b = (const float*)d_in[7];

  float* agg = (float*)d_out;                        // (B,N,S)
  float* Att = (float*)d_out + (size_t)BB * NN * SS; // (B,N,N)

  char* p = (char*)d_ws;
  unsigned short* xp  = (unsigned short*)p; p += (size_t)BB * SS * 512 * 2;   // 16.78 MB
  unsigned short* Wqp = (unsigned short*)p; p += (size_t)NN * 512 * 2;        // 0.52 MB
  unsigned short* Wkp = (unsigned short*)p; p += (size_t)NN * 512 * 2;        // 0.52 MB
  unsigned short* Qt  = (unsigned short*)p; p += (size_t)BB * NN * SS * 2;    // 16.78 MB
  unsigned short* Kt  = (unsigned short*)p; p += (size_t)BB * NN * SS * 2;    // 16.78 MB
  unsigned short* ST  = (unsigned short*)p; p += (size_t)BB * NN * NN * 2;    // 33.55 MB
  unsigned short* At2 = (unsigned short*)p; p += (size_t)BB * NN * NN * 2;    // 33.55 MB
  float* Wsub = (float*)p; p += (size_t)NN * MAXC * MAXC * 4;                 // 8.39 MB
  int* col_idx = (int*)p; p += (size_t)NN * MAXC * 4;
  int* col_cnt = (int*)p; p += NN * 4;
  int* col_off = (int*)p;

  k_prep0<<<dim3(640), dim3(256), 0, stream>>>(adj, col_idx, col_cnt,
                                               Wq_w, Wk_w, Wqp, Wkp);
  k_wsub<<<dim3(NN), dim3(256), 0, stream>>>(W, col_idx, col_cnt, col_off, Wsub);
  k_xprep<<<dim3(8192), dim3(256), 0, stream>>>(x, xp, Att);

  k_lin2<<<dim3(512), dim3(256), 0, stream>>>(Wqp, Wkp, Wq_b, Wk_b, xp, Qt, Kt);
  k_gram<<<dim3(1024), dim3(256), 0, stream>>>(Qt, Kt, ST);
  k_fused<<<dim3(8192), dim3(256), 0, stream>>>(ST, Wsub, pnw,
                                                col_idx, col_cnt, col_off,
                                                Att, At2);
  k_agg<<<dim3(512), dim3(256), 0, stream>>>(At2, xp, agg);
}

// Round 23
// 110.148 us; speedup vs baseline: 1.2008x; 1.0101x over previous
//
#include <hip/hip_runtime.h>
#include <hip/hip_fp16.h>
#include <cstdint>
#include <cmath>

#define BB 64
#define SS 256
#define NN 512
#define MAXC 64   // max nonzeros per adj column (mean ~25.6, true max ~46)

typedef float f32x4 __attribute__((ext_vector_type(4)));
typedef _Float16 half8 __attribute__((ext_vector_type(8)));

__device__ __forceinline__ unsigned short f2h(float f) {
  return __half_as_ushort(__float2half(f));
}
__device__ __forceinline__ float h2f(unsigned short u) {
  return __half2float(__ushort_as_half(u));
}

__device__ __forceinline__ void gload_lds16(const void* g, void* s) {
  __builtin_amdgcn_global_load_lds(
      (const __attribute__((address_space(1))) uint32_t*)g,
      (__attribute__((address_space(3))) uint32_t*)s, 16, 0, 0);
}

// ---------------------------------------------------------------------------
// K0: merged {per-column adjacency lists} + {f16 weight conversion} +
//     {x cast to f16} + {Att zero-fill}. Block-range dispatch:
//     [0,128): collist; [128,640): weight rows; [640,8832): x/Att.
__global__ __launch_bounds__(256) void k_prep(const float* __restrict__ adj,
                                              int* __restrict__ col_idx,
                                              int* __restrict__ col_cnt,
                                              const float* __restrict__ Wq,
                                              const float* __restrict__ Wk,
                                              unsigned short* __restrict__ Wqp,
                                              unsigned short* __restrict__ Wkp,
                                              const float* __restrict__ x,
                                              unsigned short* __restrict__ xp,
                                              float* __restrict__ Att) {
  const int bid = blockIdx.x;
  if (bid < 128) {
    const int n = bid * 4 + (threadIdx.x >> 6);
    const int lane = threadIdx.x & 63;
    int cnt = 0;
    for (int m0 = 0; m0 < NN; m0 += 64) {
      const int m = m0 + lane;
      const float a = adj[(size_t)m * NN + n];
      unsigned long long mask = __ballot(a != 0.0f);
      const int prefix = __popcll(mask & ((1ull << lane) - 1ull));
      if (a != 0.0f && cnt + prefix < MAXC) col_idx[n * MAXC + cnt + prefix] = m;
      cnt += __popcll(mask);
    }
    if (lane == 0) col_cnt[n] = (cnt > MAXC) ? MAXC : cnt;
  } else if (bid < 640) {
    const int n = bid - 128;
    const int half = threadIdx.x >> 7;          // 0: Wq, 1: Wk
    const float* src = half ? Wk : Wq;
    unsigned short* dst = half ? Wkp : Wqp;
    const int k = (threadIdx.x & 127) * 4;
    float4 v = *(const float4*)(src + (size_t)n * NN + k);
    ushort4 o;
    o.x = f2h(v.x); o.y = f2h(v.y); o.z = f2h(v.z); o.w = f2h(v.w);
    *(ushort4*)(dst + (size_t)n * 512 + k) = o;
  } else {
    const int q = bid - 640;                    // 0..8191
    const int t = threadIdx.x;
    const size_t base = ((size_t)q * 256 + t) * 4;
    float4 v = *(const float4*)(x + base);
    ushort4 o;
    o.x = f2h(v.x); o.y = f2h(v.y); o.z = f2h(v.z); o.w = f2h(v.w);
    *(ushort4*)(xp + base) = o;
    f32x4* dst = (f32x4*)(Att + (size_t)q * 2048);
    const f32x4 z = (f32x4)0.0f;
    dst[t] = z;
    dst[t + 256] = z;
  }
}

// K0b: packed W sub-blocks + per-block prefix scan. 4 waves split the ji-loop.
__global__ __launch_bounds__(256) void k_wsub(const float* __restrict__ W,
                                              const int* __restrict__ col_idx,
                                              const int* __restrict__ col_cnt,
                                              int* __restrict__ col_off,
                                              float* __restrict__ Wsub) {
  const int n = blockIdx.x;
  const int t = threadIdx.x;
  const int wave = t >> 6, lane = t & 63;
  __shared__ int lsh[MAXC];
  __shared__ int preSh;
  const int c = col_cnt[n];
  if (wave == 0) {
    int pre = 0;
#pragma unroll
    for (int i0 = 0; i0 < NN; i0 += 64) {
      const int i = i0 + lane;
      const int cc = col_cnt[i];
      pre += (i < n) ? cc * cc : 0;
    }
#pragma unroll
    for (int off = 32; off; off >>= 1) pre += __shfl_xor(pre, off);
    if (lane == 0) { col_off[n] = pre; preSh = pre; }
    if (lane < c) lsh[lane] = col_idx[n * MAXC + lane];
  }
  __syncthreads();
  if (lane < c) {
    const float* Wm = W + (size_t)lsh[lane] * NN;
    float* dst = Wsub + preSh + lane;
    for (int ji = wave; ji < c; ji += 4)
      dst[(size_t)ji * c] = Wm[lsh[ji]];
  }
}

// ---------------------------------------------------------------------------
// K3: BOTH Linears in one block (shared X staging), 2-phase prefetch pipeline.
// Single-pass f16 GEMM (K=512 -> 16 K-steps). Q out f16, K out f16.
__global__ __launch_bounds__(256, 2) void k_lin2(const unsigned short* __restrict__ Wqp,
                                                 const unsigned short* __restrict__ Wkp,
                                                 const float* __restrict__ bq,
                                                 const float* __restrict__ bk,
                                                 const unsigned short* __restrict__ xp,
                                                 unsigned short* __restrict__ Qt,
                                                 unsigned short* __restrict__ Kt) {
  __shared__ __align__(16) char sm[49152];
  const int t = threadIdx.x;
  const int w = t >> 6, l = t & 63;
  const int id = blockIdx.x;
  const int xcd = id & 7, sub = id >> 3;
  const int bn0 = (xcd * 16 + (sub >> 2)) * 128;  // r = b*256+s
  const int bm0 = (sub & 3) * 128;                // n

  const int swz = (((l & 3) ^ ((l >> 3) & 3))) * 16;
  const char* srcb[6];
  char* dstb[6];
#pragma unroll
  for (int i = 0; i < 6; i++) {
    const int ch = w * 6 + i;
    const int panel = ch >> 3, rowgrp = ch & 7;
    const int row = rowgrp * 16 + (l >> 2);
    const char* g0 = (panel == 0) ? (const char*)Wqp
                   : (panel == 1) ? (const char*)Wkp : (const char*)xp;
    const int gr = ((panel == 2) ? bn0 : bm0) + row;
    srcb[i] = g0 + (size_t)gr * 1024 + swz;
    dstb[i] = sm + panel * 8192 + rowgrp * 1024 + l * 16;
  }

  const int fr = l & 15, fg = l >> 4;
  const int mrow = (w >> 1) * 64, ncol = (w & 1) * 64;
  const int slot = (fg ^ ((fr >> 1) & 3)) * 16;
  int offQ[4], offK[4], offB[4];
#pragma unroll
  for (int fm = 0; fm < 4; fm++) {
    offQ[fm] = (mrow + fm * 16 + fr) * 64 + slot;
    offK[fm] = 8192 + (mrow + fm * 16 + fr) * 64 + slot;
    offB[fm] = 16384 + (ncol + fm * 16 + fr) * 64 + slot;
  }

  f32x4 accq[4][4], acck[4][4];
#pragma unroll
  for (int i = 0; i < 4; i++)
#pragma unroll
    for (int j = 0; j < 4; j++) { accq[i][j] = (f32x4)0.0f; acck[i][j] = (f32x4)0.0f; }

#pragma unroll
  for (int i = 0; i < 6; i++) gload_lds16(srcb[i], dstb[i]);
  __syncthreads();

  int cur = 0;
  for (int kk = 0; kk < 16; kk++) {
    if (kk + 1 < 16) {
      const int ko = (kk + 1) * 64;
      const int boff = (cur ^ 1) * 24576;
#pragma unroll
      for (int i = 0; i < 6; i++)
        gload_lds16(srcb[i] + ko, dstb[i] + boff);
    }
    const char* base = sm + cur * 24576;
    half8 afq[4], afk[4];
#pragma unroll
    for (int fm = 0; fm < 4; fm++) {
      afq[fm] = *(const half8*)(base + offQ[fm]);
      afk[fm] = *(const half8*)(base + offK[fm]);
    }
#pragma unroll
    for (int fn = 0; fn < 4; fn++) {
      const half8 bv = *(const half8*)(base + offB[fn]);
#pragma unroll
      for (int fm = 0; fm < 4; fm++) {
        accq[fm][fn] = __builtin_amdgcn_mfma_f32_16x16x32_f16(afq[fm], bv, accq[fm][fn], 0, 0, 0);
        acck[fm][fn] = __builtin_amdgcn_mfma_f32_16x16x32_f16(afk[fm], bv, acck[fm][fn], 0, 0, 0);
      }
    }
    __syncthreads();
    cur ^= 1;
  }

  // epilogue: D col = lane&15 (-> r), row = (lane>>4)*4+q (-> n)
  const int b = bn0 >> 8;
  const int sbase = (bn0 & 255) + ncol;
#pragma unroll
  for (int fm = 0; fm < 4; fm++) {
#pragma unroll
    for (int q = 0; q < 4; q++) {
      const int n = bm0 + mrow + fm * 16 + fg * 4 + q;
      const float bvq = bq[n];
      const float bvk = bk[n];
#pragma unroll
      for (int fn = 0; fn < 4; fn++) {
        const int s = sbase + fn * 16 + fr;
        Qt[((size_t)b * NN + n) * SS + s] = f2h(accq[fm][fn][q] + bvq);
        Kt[((size_t)b * NN + n) * SS + s] = f2h(acck[fm][fn][q] + bvk);
      }
    }
  }
}

// ---------------------------------------------------------------------------
// K3b: dense Gram per batch: ST[b][n][j] = <Q[b,n,:], K[b,j,:]>, f16 out.
// WIDE tile 128x256 (2x2 waves, 64x128/wave), K=256, BK=32, 2-phase prefetch.
__global__ __launch_bounds__(256, 2) void k_gram(const unsigned short* __restrict__ Qt,
                                                 const unsigned short* __restrict__ Kt,
                                                 unsigned short* __restrict__ ST) {
  __shared__ __align__(16) char sm[49152];
  const int t = threadIdx.x;
  const int w = t >> 6, l = t & 63;
  const int id = blockIdx.x;                    // 0..511
  const int xcd = id & 7, rest = id >> 3;       // rest 0..63
  const int batch = (xcd << 3) + (rest >> 3);
  const int tile = rest & 7;
  const int m0 = (tile >> 1) * 128;             // n rows (A = Q)
  const int j0 = (tile & 1) * 256;              // j rows (B = K)

  const int swz = (((l & 3) ^ ((l >> 3) & 3))) * 16;
  const char* srcb[6];
  char* dstb[6];
#pragma unroll
  for (int i = 0; i < 6; i++) {
    const int ch = w * 6 + i;                   // 24 chunks: A 0..7, B 8..23
    const int panel = (ch >= 8) ? 1 : 0;
    const int rowgrp = panel ? (ch - 8) : ch;
    const int row = rowgrp * 16 + (l >> 2);
    const char* g0 = panel ? (const char*)Kt : (const char*)Qt;
    const int gr = (panel ? j0 : m0) + row;
    srcb[i] = g0 + ((size_t)batch * 512 + gr) * 512 + swz;
    dstb[i] = sm + panel * 8192 + rowgrp * 1024 + l * 16;
  }

  const int fr = l & 15, fg = l >> 4;
  const int mrow = (w >> 1) * 64, jcol = (w & 1) * 128;
  const int slot = (fg ^ ((fr >> 1) & 3)) * 16;
  int offA[4], offB[8];
#pragma unroll
  for (int fm = 0; fm < 4; fm++)
    offA[fm] = (mrow + fm * 16 + fr) * 64 + slot;
#pragma unroll
  for (int fn = 0; fn < 8; fn++)
    offB[fn] = 8192 + (jcol + fn * 16 + fr) * 64 + slot;

  f32x4 acc[4][8];
#pragma unroll
  for (int i = 0; i < 4; i++)
#pragma unroll
    for (int j = 0; j < 8; j++) acc[i][j] = (f32x4)0.0f;

#pragma unroll
  for (int i = 0; i < 6; i++) gload_lds16(srcb[i], dstb[i]);
  __syncthreads();

  int cur = 0;
  for (int kk = 0; kk < 8; kk++) {
    if (kk + 1 < 8) {
      const int ko = (kk + 1) * 64;
      const int boff = (cur ^ 1) * 24576;
#pragma unroll
      for (int i = 0; i < 6; i++)
        gload_lds16(srcb[i] + ko, dstb[i] + boff);
    }
    const char* base = sm + cur * 24576;
    half8 af[4];
#pragma unroll
    for (int fm = 0; fm < 4; fm++)
      af[fm] = *(const half8*)(base + offA[fm]);
#pragma unroll
    for (int fn = 0; fn < 8; fn++) {
      const half8 bv = *(const half8*)(base + offB[fn]);
#pragma unroll
      for (int fm = 0; fm < 4; fm++)
        acc[fm][fn] = __builtin_amdgcn_mfma_f32_16x16x32_f16(af[fm], bv, acc[fm][fn], 0, 0, 0);
    }
    __syncthreads();
    cur ^= 1;
  }

  // epilogue: D row -> n (A rows), D col -> j (B rows)
  unsigned short* STb = ST + (size_t)batch * NN * NN;
#pragma unroll
  for (int fm = 0; fm < 4; fm++) {
#pragma unroll
    for (int q = 0; q < 4; q++) {
      const int n = m0 + mrow + fm * 16 + fg * 4 + q;
#pragma unroll
      for (int fn = 0; fn < 8; fn++) {
        const int j = j0 + jcol + fn * 16 + fr;
        STb[(size_t)n * NN + j] = f2h(acc[fm][fn][q]);
      }
    }
  }
}

// ---------------------------------------------------------------------------
// K4: fused sparse stage — ONE WAVE per (n,b) column; 4 batches per block.
// Outputs: f32 Att column scatter (d_out) AND dense f16 row Att2[b][n][:].
__global__ __launch_bounds__(256) void k_fused(const unsigned short* __restrict__ ST,
                                               const float* __restrict__ Wsub,
                                               const float* __restrict__ pnw,
                                               const int* __restrict__ col_idx,
                                               const int* __restrict__ col_cnt,
                                               const int* __restrict__ col_off,
                                               float* __restrict__ Att,
                                               unsigned short* __restrict__ Att2) {
  const int id = blockIdx.x;          // 0..8191
  const int xcd = id & 7;
  const int r = id >> 3;
  const int n = r & 511;
  const int bgrp = r >> 9;
  const int t = threadIdx.x;
  const int wave = t >> 6, lane = t & 63;
  const int b = (xcd << 3) + (bgrp << 2) + wave;

  __shared__ int   lsh[MAXC + 1];
  __shared__ float Wsh[MAXC * MAXC];
  __shared__ float vsh[4][MAXC];
  __shared__ unsigned short ush[4][NN];   // dense Att^T row build (ushort-only)

  const int c = col_cnt[n];

  // Early per-wave ST gather (hides under the cooperative staging below).
  unsigned short stv = 0;
  if (lane < c) {
    const int myIdx = col_idx[n * MAXC + lane];
    stv = ST[((size_t)b * NN + n) * NN + myIdx];
  }

  // Zero this wave's dense row (wave-private region; ushort stores only).
#pragma unroll
  for (int j = 0; j < 8; j++) ush[wave][lane * 8 + j] = 0;

  if (t < c) lsh[t] = col_idx[n * MAXC + t];
  if (t == c) lsh[c] = n;
  {
    const int cc = c * c;
    const float* Wp = Wsub + col_off[n];
    for (int i = t; i < cc; i += 256) Wsh[i] = Wp[i];
  }
  __syncthreads();   // the only block barrier

  // Step 1: publish gathered v to LDS (same-wave write/read, in-order DS).
  if (lane < c) vsh[wave][lane] = h2f(stv);

  // Step 2: aval[mi] = sum_ji Wsh[ji*c+mi] * v[ji]  (lane = mi)
  float aval = 0.0f;
  if (lane < c) {
    for (int ji = 0; ji < c; ji++)
      aval += Wsh[ji * c + lane] * vsh[wave][ji];
  }

  // Step 3: in-wave softmax over {aval[0..c), pnw[n] at diag, 512-c-1 zeros}
  const float dlg = pnw[n];
  float mval = (lane < c) ? aval : -INFINITY;
#pragma unroll
  for (int off = 32; off; off >>= 1) mval = fmaxf(mval, __shfl_xor(mval, off));
  const float colmax = fmaxf(mval, fmaxf(dlg, 0.0f));
  const float e = (lane < c) ? __expf(aval - colmax) : 0.0f;
  float sum = e;
#pragma unroll
  for (int off = 32; off; off >>= 1) sum += __shfl_xor(sum, off);
  const float denom = sum + __expf(dlg - colmax)
                    + (float)(NN - c - 1) * __expf(-colmax);
  const float inv = 1.0f / denom;

  // Step 4/5: f32 Att scatter (output) + f16 scatter into the LDS dense row.
  float* Acol = Att + (size_t)b * NN * NN + n;
  if (lane < c) {
    const float attv = e * inv;
    Acol[(size_t)lsh[lane] * NN] = attv;
    ush[wave][lsh[lane]] = f2h(attv);
  }
  if (lane == c) {
    const float dv = __expf(dlg - colmax) * inv;
    Acol[(size_t)n * NN] = dv;
    ush[wave][n] = f2h(dv);
  }

  // Dense row writeback: pack 8 ushorts/lane -> one 16B store (1KB/row).
  uint32_t pk[4];
#pragma unroll
  for (int j = 0; j < 4; j++) {
    const uint32_t lo = ush[wave][lane * 8 + j * 2];
    const uint32_t hi = ush[wave][lane * 8 + j * 2 + 1];
    pk[j] = lo | (hi << 16);
  }
  uint4 o = make_uint4(pk[0], pk[1], pk[2], pk[3]);
  *(uint4*)((char*)Att2 + ((size_t)b * NN + n) * 1024 + lane * 16) = o;
}

// ---------------------------------------------------------------------------
// K5: dense agg GEMM per batch: agg[b,n,s] = sum_m Att2[b][n][m] * xp[b,s][m].
// WIDE tile 128x256 (full N), K=512, BK=32, 2-phase prefetch.
__global__ __launch_bounds__(256, 2) void k_agg(const unsigned short* __restrict__ Att2,
                                                const unsigned short* __restrict__ xp,
                                                float* __restrict__ agg) {
  __shared__ __align__(16) char sm[49152];
  const int t = threadIdx.x;
  const int w = t >> 6, l = t & 63;
  const int id = blockIdx.x;                    // 0..255
  const int xcd = id & 7, rest = id >> 3;       // rest 0..31
  const int batch = (xcd << 3) + (rest >> 2);   // 8 batches per XCD
  const int m0 = (rest & 3) * 128;              // n rows (A = Att2); s covers all 256

  const int swz = (((l & 3) ^ ((l >> 3) & 3))) * 16;
  const char* srcb[6];
  char* dstb[6];
#pragma unroll
  for (int i = 0; i < 6; i++) {
    const int ch = w * 6 + i;                   // 24 chunks: A 0..7, B 8..23
    const int panel = (ch >= 8) ? 1 : 0;
    const int rowgrp = panel ? (ch - 8) : ch;
    const int row = rowgrp * 16 + (l >> 2);
    const char* g0 = panel ? (const char*)xp : (const char*)Att2;
    const size_t gr = panel ? ((size_t)batch * SS + row)
                            : ((size_t)batch * NN + m0 + row);
    srcb[i] = g0 + gr * 1024 + swz;
    dstb[i] = sm + panel * 8192 + rowgrp * 1024 + l * 16;
  }

  const int fr = l & 15, fg = l >> 4;
  const int mrow = (w >> 1) * 64, scol = (w & 1) * 128;
  const int slot = (fg ^ ((fr >> 1) & 3)) * 16;
  int offA[4], offB[8];
#pragma unroll
  for (int fm = 0; fm < 4; fm++)
    offA[fm] = (mrow + fm * 16 + fr) * 64 + slot;
#pragma unroll
  for (int fn = 0; fn < 8; fn++)
    offB[fn] = 8192 + (scol + fn * 16 + fr) * 64 + slot;

  f32x4 acc[4][8];
#pragma unroll
  for (int i = 0; i < 4; i++)
#pragma unroll
    for (int j = 0; j < 8; j++) acc[i][j] = (f32x4)0.0f;

#pragma unroll
  for (int i = 0; i < 6; i++) gload_lds16(srcb[i], dstb[i]);
  __syncthreads();

  int cur = 0;
  for (int kk = 0; kk < 16; kk++) {
    if (kk + 1 < 16) {
      const int ko = (kk + 1) * 64;
      const int boff = (cur ^ 1) * 24576;
#pragma unroll
      for (int i = 0; i < 6; i++)
        gload_lds16(srcb[i] + ko, dstb[i] + boff);
    }
    const char* base = sm + cur * 24576;
    half8 af[4];
#pragma unroll
    for (int fm = 0; fm < 4; fm++)
      af[fm] = *(const half8*)(base + offA[fm]);
#pragma unroll
    for (int fn = 0; fn < 8; fn++) {
      const half8 bv = *(const half8*)(base + offB[fn]);
#pragma unroll
      for (int fm = 0; fm < 4; fm++)
        acc[fm][fn] = __builtin_amdgcn_mfma_f32_16x16x32_f16(af[fm], bv, acc[fm][fn], 0, 0, 0);
    }
    __syncthreads();
    cur ^= 1;
  }

  // epilogue: D row -> n (A rows), D col -> s (B rows); agg (B,N,S) f32
  float* ab = agg + (size_t)batch * NN * SS;
#pragma unroll
  for (int fm = 0; fm < 4; fm++) {
#pragma unroll
    for (int q = 0; q < 4; q++) {
      const int n = m0 + mrow + fm * 16 + fg * 4 + q;
#pragma unroll
      for (int fn = 0; fn < 8; fn++) {
        const int s = scol + fn * 16 + fr;
        ab[(size_t)n * SS + s] = acc[fm][fn][q];
      }
    }
  }
}

// ---------------------------------------------------------------------------
extern "C" void kernel_launch(void* const* d_in, const int* in_sizes, int n_in,
                              void* d_out, int out_size, void* d_ws, size_t ws_size,
                              hipStream_t stream) {
  const float* x    = (const float*)d_in[0];
  const float* adj  = (const float*)d_in[1];
  const float* W    = (const float*)d_in[2];
  const float* pnw  = (const float*)d_in[3];
  const float* Wq_w = (const float*)d_in[4];
  const float* Wq_b = (const float*)d_in[5];
  const float* Wk_w = (const float*)d_in[6];
  const float* Wk_b = (const float*)d_in[7];

  float* agg = (float*)d_out;                        // (B,N,S)
  float* Att = (float*)d_out + (size_t)BB * NN * SS; // (B,N,N)

  char* p = (char*)d_ws;
  unsigned short* xp  = (unsigned short*)p; p += (size_t)BB * SS * 512 * 2;   // 16.78 MB
  unsigned short* Wqp = (unsigned short*)p; p += (size_t)NN * 512 * 2;        // 0.52 MB
  unsigned short* Wkp = (unsigned short*)p; p += (size_t)NN * 512 * 2;        // 0.52 MB
  unsigned short* Qt  = (unsigned short*)p; p += (size_t)BB * NN * SS * 2;    // 16.78 MB
  unsigned short* Kt  = (unsigned short*)p; p += (size_t)BB * NN * SS * 2;    // 16.78 MB
  unsigned short* ST  = (unsigned short*)p; p += (size_t)BB * NN * NN * 2;    // 33.55 MB
  unsigned short* At2 = (unsigned short*)p; p += (size_t)BB * NN * NN * 2;    // 33.55 MB
  float* Wsub = (float*)p; p += (size_t)NN * MAXC * MAXC * 4;                 // 8.39 MB
  int* col_idx = (int*)p; p += (size_t)NN * MAXC * 4;
  int* col_cnt = (int*)p; p += NN * 4;
  int* col_off = (int*)p;

  k_prep<<<dim3(8832), dim3(256), 0, stream>>>(adj, col_idx, col_cnt,
                                               Wq_w, Wk_w, Wqp, Wkp,
                                               x, xp, Att);
  k_wsub<<<dim3(NN), dim3(256), 0, stream>>>(W, col_idx, col_cnt, col_off, Wsub);

  k_lin2<<<dim3(512), dim3(256), 0, stream>>>(Wqp, Wkp, Wq_b, Wk_b, xp, Qt, Kt);
  k_gram<<<dim3(512), dim3(256), 0, stream>>>(Qt, Kt, ST);
  k_fused<<<dim3(8192), dim3(256), 0, stream>>>(ST, Wsub, pnw,
                                                col_idx, col_cnt, col_off,
                                                Att, At2);
  k_agg<<<dim3(256), dim3(256), 0, stream>>>(At2, xp, agg);
}